// Round 5
// baseline (602.616 us; speedup 1.0000x reference)
//
#include <hip/hip_runtime.h>
#include <hip/hip_bf16.h>
#include <cstdint>
#include <cstddef>
#include <initializer_list>

// Problem constants
#define WE    300
#define TEF   10
#define SLEN  24
#define HL    75      // H_LSTM
#define G4    300     // 4*HL
#define HG    77      // H_GRU
#define G3    231     // 3*HG
#define CLS   27
#define DIN   7210
#define NSTEP 4608
#define LBI   16      // LSTM segment burn-in (worst-case window gets >=11 steps; err ~2e-4 state -> ~1e-7 out)

typedef short    s16x8 __attribute__((ext_vector_type(8)));
typedef float    f32x4 __attribute__((ext_vector_type(4)));
typedef _Float16 h2_t  __attribute__((ext_vector_type(2)));

static __device__ __forceinline__ unsigned short f2bf(float f) {
  unsigned u = __builtin_bit_cast(unsigned, f);
  unsigned r = u + 0x7fffu + ((u >> 16) & 1u);   // RNE
  return (unsigned short)(r >> 16);
}
static __device__ __forceinline__ unsigned packbf(float2 v) {
  return (unsigned)f2bf(v.x) | ((unsigned)f2bf(v.y) << 16);
}

static __device__ __forceinline__ float fast_exp2(float x) {
#if __has_builtin(__builtin_amdgcn_exp2f)
  return __builtin_amdgcn_exp2f(x);
#else
  return __exp2f(x);
#endif
}
static __device__ __forceinline__ float fast_rcp(float x) {
#if __has_builtin(__builtin_amdgcn_rcpf)
  return __builtin_amdgcn_rcpf(x);
#else
  return 1.0f / x;
#endif
}
static __device__ __forceinline__ float sigm(float x) {
  return fast_rcp(1.0f + fast_exp2(-1.4426950408889634f * x));
}
static __device__ __forceinline__ float tanh_f(float x) {
  return 2.0f * fast_rcp(1.0f + fast_exp2(-2.8853900817779268f * x)) - 1.0f;
}

// LDS-only barrier (global prefetch stays in flight)
static __device__ __forceinline__ void lds_barrier() {
  __asm__ volatile("s_waitcnt lgkmcnt(0)\n\ts_barrier" ::: "memory");
}

#if __has_builtin(__builtin_amdgcn_update_dpp)
static __device__ __forceinline__ float qxor1(float v) {
  return __builtin_bit_cast(float, __builtin_amdgcn_update_dpp(0, __builtin_bit_cast(int, v), 177, 0xf, 0xf, false));
}
static __device__ __forceinline__ float qxor2(float v) {
  return __builtin_bit_cast(float, __builtin_amdgcn_update_dpp(0, __builtin_bit_cast(int, v), 78, 0xf, 0xf, false));
}
static __device__ __forceinline__ float qxor3(float v) {
  return __builtin_bit_cast(float, __builtin_amdgcn_update_dpp(0, __builtin_bit_cast(int, v), 27, 0xf, 0xf, false));
}
#else
static __device__ __forceinline__ float qxor1(float v) { return __shfl_xor(v, 1, 64); }
static __device__ __forceinline__ float qxor2(float v) { return __shfl_xor(v, 2, 64); }
static __device__ __forceinline__ float qxor3(float v) { return __shfl_xor(v, 3, 64); }
#endif

#if __has_builtin(__builtin_amdgcn_fdot2)
#define FDOT2(a, b, c) __builtin_amdgcn_fdot2((a), (b), (c), false)
#else
#define FDOT2(a, b, c) ((c) + (float)(a).x * (float)(b).x + (float)(a).y * (float)(b).y)
#endif

// ---------------------------------------------------------------------------
// Wt[n][k] = lstm_W[k][n], bf16, zero-padded to 320x320
// ---------------------------------------------------------------------------
__global__ __launch_bounds__(256) void k_prep_wt(const float* __restrict__ W,
                                                 unsigned short* __restrict__ Wt) {
  int idx = blockIdx.x * 256 + threadIdx.x;
  if (idx >= 320 * 320) return;
  int n = idx / 320, k = idx - n * 320;
  float v = (n < G4 && k < WE) ? W[k * G4 + n] : 0.0f;
  Wt[idx] = f2bf(v);
}

// ---------------------------------------------------------------------------
// K1: XWc = we @ lstm_W + lstm_b (bias folded here so k_lstm drops 3 regs).
// Double-buffered LDS, one barrier per kb; A staged f32->bf16 via register
// prefetch. grid (NC*24/128, 2), 256 threads.
// ---------------------------------------------------------------------------
__global__ __launch_bounds__(256) void k_gemm(const float* __restrict__ X,
                                              const unsigned short* __restrict__ Wt,
                                              const float* __restrict__ bvec,
                                              float* __restrict__ XWc, int n0) {
  __shared__ __align__(16) uint4 Ab[2][516];   // 16.5 KB
  __shared__ __align__(16) uint4 Bb[2][648];   // 20.7 KB
  const int tid = threadIdx.x;
  const int wave = tid >> 6, lane = tid & 63;
  const int mlo = blockIdx.x * 128;
  const int nbase = blockIdx.y * 160;
  const int mrow = lane & 15, q4 = lane >> 4;

  // A staging: thread covers row rowA, bf16-cols [kb*32 + chalf*16, +16)
  const int rowA = tid >> 1, chalf = tid & 1;
  const int mg = n0 * 24 + mlo + rowA;
  const int an = mg / 24, at = mg - an * 24;
  const float2* asrc2 = (const float2*)(X + (size_t)an * DIN + at * WE);  // 8B-aligned

  // B staging: thread covers slots s, s+256, s+512(tid<128); rb=row, sub=k-grp
  const int s0 = tid, s1 = tid + 256, s2 = tid + 512;
  const int rb0 = s0 % 160, sub0 = s0 / 160;
  const int rb1 = s1 % 160, sub1 = s1 / 160;
  const int rb2 = s2 % 160, sub2 = s2 / 160;
  const bool h2b = (tid < 128);
  const unsigned short* b0 = Wt + (size_t)(nbase + rb0) * 320 + sub0 * 8;
  const unsigned short* b1 = Wt + (size_t)(nbase + rb1) * 320 + sub1 * 8;
  const unsigned short* b2 = Wt + (size_t)(nbase + rb2) * 320 + sub2 * 8;

  f32x4 acc[2][10];
#pragma unroll
  for (int i = 0; i < 2; ++i)
#pragma unroll
    for (int j = 0; j < 10; ++j) { acc[i][j][0] = 0.f; acc[i][j][1] = 0.f; acc[i][j][2] = 0.f; acc[i][j][3] = 0.f; }

  // prologue: stage kb=0 into buf 0
  {
    float2 af2[8];
#pragma unroll
    for (int p = 0; p < 8; ++p) af2[p] = asrc2[(chalf * 16 + 2 * p) >> 1];  // cols 0..31 < 300
    uint4 r0 = *(const uint4*)b0;
    uint4 r1 = *(const uint4*)b1;
    uint4 r2 = h2b ? *(const uint4*)b2 : uint4{0, 0, 0, 0};
    uint4 w0, w1;
    w0.x = packbf(af2[0]); w0.y = packbf(af2[1]); w0.z = packbf(af2[2]); w0.w = packbf(af2[3]);
    w1.x = packbf(af2[4]); w1.y = packbf(af2[5]); w1.z = packbf(af2[6]); w1.w = packbf(af2[7]);
    Ab[0][(chalf * 2 + 0) * 129 + rowA] = w0;
    Ab[0][(chalf * 2 + 1) * 129 + rowA] = w1;
    Bb[0][sub0 * 161 + rb0] = r0;
    Bb[0][sub1 * 161 + rb1] = r1;
    if (h2b) Bb[0][sub2 * 161 + rb2] = r2;
  }
  __syncthreads();

  for (int kb = 0; kb < 10; ++kb) {
    const int par = kb & 1;
    float2 af2[8];
    uint4 r0, r1, r2;
    if (kb < 9) {
      const int base = (kb + 1) * 32 + chalf * 16;
#pragma unroll
      for (int p = 0; p < 8; ++p) {
        int cc = base + 2 * p;
        if (cc < WE) af2[p] = asrc2[cc >> 1];
        else { af2[p].x = 0.f; af2[p].y = 0.f; }
      }
      const int ko = (kb + 1) * 32;
      r0 = *(const uint4*)(b0 + ko);
      r1 = *(const uint4*)(b1 + ko);
      if (h2b) r2 = *(const uint4*)(b2 + ko);
    }
    s16x8 fa0 = __builtin_bit_cast(s16x8, Ab[par][q4 * 129 + wave * 32 + mrow]);
    s16x8 fa1 = __builtin_bit_cast(s16x8, Ab[par][q4 * 129 + wave * 32 + 16 + mrow]);
#pragma unroll
    for (int ni = 0; ni < 10; ++ni) {
      s16x8 fb = __builtin_bit_cast(s16x8, Bb[par][q4 * 161 + ni * 16 + mrow]);
      acc[0][ni] = __builtin_amdgcn_mfma_f32_16x16x32_bf16(fa0, fb, acc[0][ni], 0, 0, 0);
      acc[1][ni] = __builtin_amdgcn_mfma_f32_16x16x32_bf16(fa1, fb, acc[1][ni], 0, 0, 0);
    }
    if (kb < 9) {
      uint4 w0, w1;
      w0.x = packbf(af2[0]); w0.y = packbf(af2[1]); w0.z = packbf(af2[2]); w0.w = packbf(af2[3]);
      w1.x = packbf(af2[4]); w1.y = packbf(af2[5]); w1.z = packbf(af2[6]); w1.w = packbf(af2[7]);
      Ab[par ^ 1][(chalf * 2 + 0) * 129 + rowA] = w0;
      Ab[par ^ 1][(chalf * 2 + 1) * 129 + rowA] = w1;
      Bb[par ^ 1][sub0 * 161 + rb0] = r0;
      Bb[par ^ 1][sub1 * 161 + rb1] = r1;
      if (h2b) Bb[par ^ 1][sub2 * 161 + rb2] = r2;
    }
    __syncthreads();
  }

  // epilogue: C layout col=lane&15, row=(lane>>4)*4+reg; add lstm_b here
#pragma unroll
  for (int mi = 0; mi < 2; ++mi) {
#pragma unroll
    for (int ni = 0; ni < 10; ++ni) {
      int col = nbase + ni * 16 + mrow;
      if (col < G4) {
        float bv = bvec[col];
#pragma unroll
        for (int reg = 0; reg < 4; ++reg) {
          int m = mlo + wave * 32 + mi * 16 + q4 * 4 + reg;
          XWc[(size_t)m * G4 + col] = acc[mi][ni][reg] + bv;
        }
      }
    }
  }
}

// ---------------------------------------------------------------------------
// K2: segmented LSTM, 3 waves/block (192 thr). grid (24 chains, nseg segs).
// Quad Q (0..47) owns elements {Q, Q+48(<75)}; lane-in-quad = gate.
// WORLD MODEL (fixed in r5): FETCH arithmetic proves chunks==2 (XWc chunk
// 66.4MB + burn-in re-reads ~11MB + line overhead = 82MB measured). So the
// iteration is 2x k_lstm(241) + 2x k_gemm(~45) + small = 601us; k_lstm was
// NEVER dispatch-capacity-bound (576 blocks << 1280 capacity). It is a
// latency-bound serial recurrence at ~2.15us/step, FLAT in occupancy
// (4.5 w/CU -> 2.26, 6.75 w/CU -> 2.15). Lever: fewer sequential steps x
// more concurrent chains -> S=48 (host-side only; kernel unchanged).
// VGPR=88 @ waves_per_eu(2) verified no-spill in r4.
// ---------------------------------------------------------------------------
#define LSTM_DOT2()                                                                    \
  {                                                                                    \
    float a0x = 0.f, a0y = 0.f, a0z = 0.f, a0w = 0.f;                                  \
    float a1x = 0.f, a1y = 0.f, a1z = 0.f, a1w = 0.f;                                  \
    _Pragma("unroll")                                                                  \
    for (int p = 0; p < 9; ++p) {                                                      \
      uint4 w = hb4[p];                                                                \
      h2_t wx = __builtin_bit_cast(h2_t, w.x), wy = __builtin_bit_cast(h2_t, w.y);     \
      h2_t wz = __builtin_bit_cast(h2_t, w.z), ww = __builtin_bit_cast(h2_t, w.w);     \
      a0x = FDOT2(u0[4 * p + 0], wx, a0x); a0y = FDOT2(u0[4 * p + 1], wy, a0y);        \
      a0z = FDOT2(u0[4 * p + 2], wz, a0z); a0w = FDOT2(u0[4 * p + 3], ww, a0w);        \
      a1x = FDOT2(u1[4 * p + 0], wx, a1x); a1y = FDOT2(u1[4 * p + 1], wy, a1y);        \
      a1z = FDOT2(u1[4 * p + 2], wz, a1z); a1w = FDOT2(u1[4 * p + 3], ww, a1w);        \
    }                                                                                  \
    {                                                                                  \
      uint2 wt_ = *hbt;                                                                \
      h2_t wx = __builtin_bit_cast(h2_t, wt_.x), wy = __builtin_bit_cast(h2_t, wt_.y); \
      a0x = FDOT2(u0[36], wx, a0x); a0y = FDOT2(u0[37], wy, a0y);                      \
      a1x = FDOT2(u1[36], wx, a1x); a1y = FDOT2(u1[37], wy, a1y);                      \
    }                                                                                  \
    z0 = (a0x + a0y) + (a0z + a0w);                                                    \
    z1 = (a1x + a1y) + (a1z + a1w);                                                    \
  }

#define LSTM_ACT(Z, C, H)                                                              \
  {                                                                                    \
    float ss = fast_rcp(1.0f + fast_exp2((Z)*km));                                     \
    float act = isg ? (2.0f * ss - 1.0f) : ss;                                         \
    float fg = qxor1(act);                                                             \
    float gg = qxor2(act);                                                             \
    float og = qxor3(act);                                                             \
    (C) = fmaf(fg, (C), act * gg);                                                     \
    (H) = og * tanh_f((C));                                                            \
  }

#define LSTM_STEP(I, PAR)                                                              \
  {                                                                                    \
    bool ld = (m + (I) + 2 < count);                                                   \
    int nidx = (m + (I) + 2) * 7200;                                                   \
    float pn0 = ld ? xw[nidx] : 0.f;                                                   \
    float pn1 = ld ? xw[nidx + d1] : 0.f;                                              \
    const uint4* hb4 = (const uint4*)(&hbuf[PAR][0]);                                  \
    const uint2* hbt = (const uint2*)(&hbuf[PAR][72]);                                 \
    float z0, z1;                                                                      \
    LSTM_DOT2()                                                                        \
    z0 += pf0[(I) & 1]; z1 += pf1[(I) & 1];                                            \
    LSTM_ACT(z0, c0r, h0r)                                                             \
    LSTM_ACT(z1, c1r, h1r)                                                             \
    pf0[(I) & 1] = pn0; pf1[(I) & 1] = pn1;                                            \
    if (g == 0) {                                                                      \
      unsigned short* hw = &hbuf[(PAR) ^ 1][0];                                        \
      hw[e0] = __builtin_bit_cast(unsigned short, (_Float16)h0r);                      \
      if (has1) hw[e1] = __builtin_bit_cast(unsigned short, (_Float16)h1r);            \
      int ng = gbase + m + (I);                                                        \
      int bi = ng / 18;                                                                \
      int rr = ng - bi * 18;                                                           \
      if (rr >= 12) {                                                                  \
        float aw = A_lds[rr - 12];                                                     \
        accA0 = fmaf(aw, h0r, accA0);                                                  \
        accA1 = fmaf(aw, h1r, accA1);                                                  \
        if (rr == 17) {                                                                \
          if (ng >= out_lo) {                                                          \
            float* Pp = P + ((size_t)((t << 8) + bi)) * 76;                            \
            Pp[e0] = accA0;                                                            \
            if (has1) Pp[e1] = accA1;                                                  \
          }                                                                            \
          accA0 = 0.f; accA1 = 0.f;                                                    \
        }                                                                              \
      }                                                                                \
    }                                                                                  \
    lds_barrier();                                                                     \
  }

__global__ __launch_bounds__(192) __attribute__((amdgpu_waves_per_eu(2)))
void k_lstm(const float* __restrict__ XWc,
            const float* __restrict__ U,
            const float* __restrict__ Atw,
            float* __restrict__ P,
            float* __restrict__ Sbuf,
            int n0, int S, int nseg,
            int first, int parity) {
  __shared__ __align__(16) unsigned short hbuf[2][80];
  __shared__ float A_lds[8];
  const int tid = threadIdx.x;          // 0..191
  const int t = blockIdx.x;
  const int seg = blockIdx.y;
  const int g = tid & 3;
  const int Q = tid >> 2;               // 0..47
  const bool isg = (g == 2);
  const float km = isg ? -2.8853900817779268f : -1.4426950408889634f;

  const int e0 = Q, e1 = Q + 48;
  const bool has1 = (e1 < HL);          // Q < 27
  const int c0 = g * 75 + e0;
  const int c1 = c0 + (has1 ? 48 : 0);
  const int d1 = has1 ? 48 : 0;

  const int start = seg * S - (seg ? LBI : 0);
  const int count = S + (seg ? LBI : 0);
  const int gbase = n0 + start;
  const int out_lo = n0 + seg * S;

  if (tid < 6) A_lds[tid] = Atw[tid];
  if (tid < 80) { hbuf[0][tid] = 0; hbuf[1][tid] = 0; }

  h2_t u0[38], u1[38];
#pragma unroll
  for (int p = 0; p < 38; ++p) {
    int r0 = 2 * p, r1 = 2 * p + 1;
    float va0 = U[r0 * G4 + c0];
    float vb0 = (r1 < HL) ? U[r1 * G4 + c0] : 0.f;
    float va1 = has1 ? U[r0 * G4 + c1] : 0.f;
    float vb1 = (has1 && r1 < HL) ? U[r1 * G4 + c1] : 0.f;
    h2_t w;
    w.x = (_Float16)va0; w.y = (_Float16)vb0; u0[p] = w;
    w.x = (_Float16)va1; w.y = (_Float16)vb1; u1[p] = w;
  }

  float c0r = 0.f, c1r = 0.f;
  float h0r = 0.f, h1r = 0.f;
  float accA0 = 0.f, accA1 = 0.f;

  if (g == 0) {
    if (seg == 0 && !first) {
      const float* Sp = Sbuf + (size_t)(parity * 24 + t) * 160;
      c0r = Sp[e0]; h0r = Sp[80 + e0];
      if (has1) { c1r = Sp[e1]; h1r = Sp[80 + e1]; }
    }
    hbuf[0][e0] = __builtin_bit_cast(unsigned short, (_Float16)h0r);
    if (has1) hbuf[0][e1] = __builtin_bit_cast(unsigned short, (_Float16)h1r);
  }

  const float* xw = XWc + (size_t)start * 7200 + (size_t)t * G4 + c0;
  float pf0[2], pf1[2];
#pragma unroll
  for (int d = 0; d < 2; ++d) {
    pf0[d] = xw[d * 7200];
    pf1[d] = xw[d * 7200 + d1];
  }
  __syncthreads();

  for (int m = 0; m < count; m += 4) {
    LSTM_STEP(0, 0)
    LSTM_STEP(1, 1)
    LSTM_STEP(2, 0)
    LSTM_STEP(3, 1)
  }

  if (g == 0 && seg == nseg - 1) {
    float* Sp = Sbuf + (size_t)((parity ^ 1) * 24 + t) * 160;
    Sp[e0] = c0r; Sp[80 + e0] = h0r;
    if (has1) { Sp[e1] = c1r; Sp[80 + e1] = h1r; }
  }
}

// ---------------------------------------------------------------------------
// K3: hA -> ctx (ut==2) -> xg = ctx@gru_W + gru_b[0]. grid 256, 320 thr.
// ---------------------------------------------------------------------------
__global__ __launch_bounds__(320) void k_ctx(const float* __restrict__ P,
                                             const float* __restrict__ Wtw,
                                             const float* __restrict__ btw,
                                             const float* __restrict__ Atw,
                                             const float* __restrict__ Btw,
                                             const float* __restrict__ X,
                                             const float* __restrict__ Wg,
                                             const float* __restrict__ bg,
                                             float* __restrict__ xg) {
  __shared__ float hA[76];
  __shared__ float ctx[312];
  const int b = blockIdx.x, j = threadIdx.x;
  if (j < HL) {
    float s = 0.f;
    for (int t = 0; t < SLEN; ++t) s += P[((t << 8) + b) * 76 + j];
    hA[j] = s * (1.0f / 24.0f);
  }
  __syncthreads();
  if (j < G4) {
    float SA = Atw[0] + Atw[1] + Atw[2] + Atw[3] + Atw[4] + Atw[5];
    float s = SA * btw[j];
    for (int k = 0; k < HL; ++k) s = fmaf(hA[k], Wtw[k * G4 + j], s);
    ctx[j] = s * (1000.0f / 1001.0f) + Btw[0];
  } else if (j < 310) {
    int f = j - G4;
    float s = 0.f;
#pragma unroll
    for (int nt = 0; nt < 6; ++nt)
      s = fmaf(Atw[nt], X[(size_t)((b * 3 + 2) * 6 + nt) * DIN + 7200 + f], s);
    ctx[j] = s * (1.0f / 1001.0f) + Btw[0];
  }
  __syncthreads();
  if (j < G3) {
    float s = bg[j];
    for (int f = 0; f < 310; ++f) s = fmaf(ctx[f], Wg[f * G3 + j], s);
    xg[b * 240 + j] = s;
  }
}

// ---------------------------------------------------------------------------
// K5: segmented GRU (chain ut==2). grid 16 blocks x 256 thr.
// ---------------------------------------------------------------------------
#define GRU_STEP(B, PF)                                                                \
  {                                                                                    \
    if (q < G3) {                                                                      \
      const float4* h4 = (const float4*)gh;                                            \
      float a0 = b1, a1 = 0.f, a2 = 0.f, a3 = 0.f;                                     \
      _Pragma("unroll")                                                                \
      for (int p = 0; p < 20; ++p) {                                                   \
        float4 hv = h4[p];                                                             \
        a0 = fmaf(ug[4 * p + 0], hv.x, a0);                                            \
        a1 = fmaf(ug[4 * p + 1], hv.y, a1);                                            \
        a2 = fmaf(ug[4 * p + 2], hv.z, a2);                                            \
        a3 = fmaf(ug[4 * p + 3], hv.w, a3);                                            \
      }                                                                                \
      float rs = (a0 + a1) + (a2 + a3);                                                \
      float pnew = ((B) + 2 < 256) ? xg[((B) + 2) * 240 + q] : 0.f;                    \
      if (q < HG) {                                                                    \
        zreg = sigm((PF) + rs);                                                        \
      } else if (q < 154) {                                                            \
        rbuf[q - 77] = sigm((PF) + rs);                                                \
      } else {                                                                         \
        xkeep = (PF);                                                                  \
        rkeep = rs;                                                                    \
      }                                                                                \
      (PF) = pnew;                                                                     \
    }                                                                                  \
    lds_barrier();                                                                     \
    if (q >= 154 && q < G3) hhb[q - 154] = tanh_f(xkeep + rbuf[q - 154] * rkeep);      \
    lds_barrier();                                                                     \
    if (q < HG) {                                                                      \
      float hh = hhb[q];                                                               \
      hq = zreg * hq + (1.0f - zreg) * hh;                                             \
      gh[q] = hq;                                                                      \
      if ((B) >= out_lo) Hg[(B) * 80 + q] = hq;                                        \
    }                                                                                  \
    lds_barrier();                                                                     \
  }

__global__ __launch_bounds__(256) void k_gru(const float* __restrict__ Ug,
                                             const float* __restrict__ bg,
                                             const float* __restrict__ xg,
                                             float* __restrict__ Hg) {
  __shared__ __align__(16) float gh[80];
  __shared__ float rbuf[77];
  __shared__ float hhb[77];
  const int q = threadIdx.x;
  const int b0 = blockIdx.x;
  const int out_lo = b0 * 16;
  const int start = b0 ? (out_lo - 16) : 0;
  const int end = out_lo + 16;
  float ug[80];
  float b1 = 0.f;
  if (q < G3) {
    b1 = bg[G3 + q];
#pragma unroll
    for (int k = 0; k < 80; ++k) ug[k] = (k < HG) ? Ug[k * G3 + q] : 0.f;
  }
  if (q < 80) gh[q] = 0.f;
  float hq = 0.f, zreg = 0.f, xkeep = 0.f, rkeep = 0.f;
  float pf0 = (q < G3) ? xg[start * 240 + q] : 0.f;
  float pf1 = (q < G3) ? xg[(start + 1) * 240 + q] : 0.f;
  __syncthreads();
  for (int b = start; b < end; b += 2) {
    GRU_STEP(b, pf0)
    GRU_STEP(b + 1, pf1)
  }
}

// ---------------------------------------------------------------------------
__global__ __launch_bounds__(64) void k_out(const float* __restrict__ Hg,
                                            const float* __restrict__ Wl,
                                            const float* __restrict__ bl,
                                            float* __restrict__ out) {
  __shared__ float lb[CLS];
  __shared__ float eb[CLS];
  const int b = blockIdx.x, j = threadIdx.x;
  float lg = 0.f;
  if (j < CLS) {
    lg = bl[j];
    for (int k = 0; k < HG; ++k) lg = fmaf(Hg[b * 80 + k], Wl[k * CLS + j], lg);
    lb[j] = lg;
  }
  __syncthreads();
  float ex = 0.f;
  if (j < CLS) {
    float m = lb[0];
    for (int i = 1; i < CLS; ++i) m = fmaxf(m, lb[i]);
    ex = fast_exp2((lg - m) * 1.4426950408889634f);
    eb[j] = ex;
  }
  __syncthreads();
  if (j < CLS) {
    float s = 0.f;
    for (int i = 0; i < CLS; ++i) s += eb[i];
    out[b * CLS + j] = ex / s;
  }
}

// ---------------------------------------------------------------------------
extern "C" void kernel_launch(void* const* d_in, const int* in_sizes, int n_in,
                              void* d_out, int out_size, void* d_ws, size_t ws_size,
                              hipStream_t stream) {
  const float* X    = (const float*)d_in[0];
  const float* lW   = (const float*)d_in[1];
  const float* lU   = (const float*)d_in[2];
  const float* lb   = (const float*)d_in[3];
  const float* twW  = (const float*)d_in[4];
  const float* twb  = (const float*)d_in[5];
  const float* Atw  = (const float*)d_in[6];
  const float* Btw  = (const float*)d_in[7];
  const float* gW   = (const float*)d_in[8];
  const float* gU   = (const float*)d_in[9];
  const float* gb   = (const float*)d_in[10];
  const float* linW = (const float*)d_in[11];
  const float* linb = (const float*)d_in[12];
  float* out = (float*)d_out;

  char* ws = (char*)d_ws;
  unsigned short* Wt = (unsigned short*)(ws + 0);        // 204800
  float* P   = (float*)(ws + 204800);                    // 1867776
  float* Sb  = (float*)(ws + 2072576);                   // 30720
  float* xg  = (float*)(ws + 2103296);                   // 245760
  float* Hg  = (float*)(ws + 2349056);                   // 81920
  float* XWc = (float*)(ws + 2430976);                   // NC*24*300*4 (full: 132.7 MB)

  const size_t fixed = 2430976;
  int NC = 144;
  for (int k : {32, 16, 8, 4, 2, 1}) {
    size_t need = fixed + (size_t)144 * k * 28800;
    if (need <= ws_size) { NC = 144 * k; break; }
  }
  const int chunks = NSTEP / NC;
  // Segmentation: smallest S (most parallel chains) such that the grid of
  // 3-wave blocks stays within single-round capacity (88 VGPR -> 16 waves/CU
  // -> 5 blocks/CU -> 1280 blocks). For NC=2304: S=48, nseg=48, 1152 blocks,
  // 64 sequential steps/chunk (vs 112 at S=96).
  int S = NC, nseg = 1;
  for (int s : {48, 64, 96, 128, 192}) {
    if (NC % s == 0 && 24 * (NC / s) <= 1280) { S = s; nseg = NC / s; break; }
  }

  k_prep_wt<<<dim3(400), dim3(256), 0, stream>>>(lW, Wt);
  for (int ci = 0; ci < chunks; ++ci) {
    const int n0 = ci * NC;
    k_gemm<<<dim3(NC * 24 / 128, 2), dim3(256), 0, stream>>>(X, Wt, lb, XWc, n0);
    k_lstm<<<dim3(24, nseg), dim3(192), 0, stream>>>(XWc, lU, Atw, P, Sb,
                                                     n0, S, nseg,
                                                     ci == 0 ? 1 : 0, ci & 1);
  }
  k_ctx<<<dim3(256), dim3(320), 0, stream>>>(P, twW, twb, Atw, Btw, X, gW, gb, xg);
  k_gru<<<dim3(16), dim3(256), 0, stream>>>(gU, gb, xg, Hg);
  k_out<<<dim3(256), dim3(64), 0, stream>>>(Hg, linW, linb, out);
}

// Round 6
// 448.088 us; speedup vs baseline: 1.3449x; 1.3449x over previous
//
#include <hip/hip_runtime.h>
#include <hip/hip_bf16.h>
#include <cstdint>
#include <cstddef>
#include <initializer_list>

// Problem constants
#define WE    300
#define TEF   10
#define SLEN  24
#define HL    75      // H_LSTM
#define G4    300     // 4*HL
#define HG    77      // H_GRU
#define G3    231     // 3*HG
#define CLS   27
#define DIN   7210
#define NSTEP 4608
#define LBI   16      // LSTM segment burn-in (same modular warm-up guarantees for S in {24,48,96})

typedef short    s16x8 __attribute__((ext_vector_type(8)));
typedef float    f32x4 __attribute__((ext_vector_type(4)));
typedef _Float16 f16x8 __attribute__((ext_vector_type(8)));

static __device__ __forceinline__ unsigned short f2bf(float f) {
  unsigned u = __builtin_bit_cast(unsigned, f);
  unsigned r = u + 0x7fffu + ((u >> 16) & 1u);   // RNE
  return (unsigned short)(r >> 16);
}
static __device__ __forceinline__ unsigned packbf(float2 v) {
  return (unsigned)f2bf(v.x) | ((unsigned)f2bf(v.y) << 16);
}

static __device__ __forceinline__ float fast_exp2(float x) {
#if __has_builtin(__builtin_amdgcn_exp2f)
  return __builtin_amdgcn_exp2f(x);
#else
  return __exp2f(x);
#endif
}
static __device__ __forceinline__ float fast_rcp(float x) {
#if __has_builtin(__builtin_amdgcn_rcpf)
  return __builtin_amdgcn_rcpf(x);
#else
  return 1.0f / x;
#endif
}
static __device__ __forceinline__ float sigm(float x) {
  return fast_rcp(1.0f + fast_exp2(-1.4426950408889634f * x));
}
static __device__ __forceinline__ float tanh_f(float x) {
  return 2.0f * fast_rcp(1.0f + fast_exp2(-2.8853900817779268f * x)) - 1.0f;
}

// LDS-only barrier (global prefetch stays in flight)
static __device__ __forceinline__ void lds_barrier() {
  __asm__ volatile("s_waitcnt lgkmcnt(0)\n\ts_barrier" ::: "memory");
}

// ---------------------------------------------------------------------------
// Wt[n][k] = lstm_W[k][orig(n)], bf16, zero-padded to 320x320.
// COLUMN PERMUTATION: n is gate-interleaved: n = 4*e + gate, orig = gate*75+e.
// So XWc (and U below) carry interleaved columns -> MFMA D-frag holds all 4
// gates of one element in one lane's 4 regs (activation is lane-local).
// ---------------------------------------------------------------------------
__global__ __launch_bounds__(256) void k_prep_wt(const float* __restrict__ W,
                                                 unsigned short* __restrict__ Wt) {
  int idx = blockIdx.x * 256 + threadIdx.x;
  if (idx >= 320 * 320) return;
  int n = idx / 320, k = idx - n * 320;
  float v = 0.0f;
  if (n < G4 && k < WE) {
    int e = n >> 2, g = n & 3;
    v = W[k * G4 + (g * 75 + e)];
  }
  Wt[idx] = f2bf(v);
}

// Upp[c][k] f16, [304][96]: Upp[c][k] = lstm_U[k][orig(c)], zero-padded.
__global__ __launch_bounds__(256) void k_prep_u(const float* __restrict__ U,
                                                unsigned short* __restrict__ Upp) {
  int idx = blockIdx.x * 256 + threadIdx.x;
  if (idx >= 304 * 96) return;
  int c = idx / 96, k = idx - c * 96;
  float v = 0.f;
  int e = c >> 2, g = c & 3;
  if (e < HL && k < HL) v = U[k * G4 + g * 75 + e];
  _Float16 hv = (_Float16)v;
  Upp[idx] = __builtin_bit_cast(unsigned short, hv);
}

// ---------------------------------------------------------------------------
// K1: XWc = we @ lstm_W + lstm_b (permuted cols; bias indexed via orig(col)).
// Double-buffered LDS, one barrier per kb. grid (NC*24/128, 2), 256 threads.
// ---------------------------------------------------------------------------
__global__ __launch_bounds__(256) void k_gemm(const float* __restrict__ X,
                                              const unsigned short* __restrict__ Wt,
                                              const float* __restrict__ bvec,
                                              float* __restrict__ XWc, int n0) {
  __shared__ __align__(16) uint4 Ab[2][516];   // 16.5 KB
  __shared__ __align__(16) uint4 Bb[2][648];   // 20.7 KB
  const int tid = threadIdx.x;
  const int wave = tid >> 6, lane = tid & 63;
  const int mlo = blockIdx.x * 128;
  const int nbase = blockIdx.y * 160;
  const int mrow = lane & 15, q4 = lane >> 4;

  const int rowA = tid >> 1, chalf = tid & 1;
  const int mg = n0 * 24 + mlo + rowA;
  const int an = mg / 24, at = mg - an * 24;
  const float2* asrc2 = (const float2*)(X + (size_t)an * DIN + at * WE);  // 8B-aligned

  const int s0 = tid, s1 = tid + 256, s2 = tid + 512;
  const int rb0 = s0 % 160, sub0 = s0 / 160;
  const int rb1 = s1 % 160, sub1 = s1 / 160;
  const int rb2 = s2 % 160, sub2 = s2 / 160;
  const bool h2b = (tid < 128);
  const unsigned short* b0 = Wt + (size_t)(nbase + rb0) * 320 + sub0 * 8;
  const unsigned short* b1 = Wt + (size_t)(nbase + rb1) * 320 + sub1 * 8;
  const unsigned short* b2 = Wt + (size_t)(nbase + rb2) * 320 + sub2 * 8;

  f32x4 acc[2][10];
#pragma unroll
  for (int i = 0; i < 2; ++i)
#pragma unroll
    for (int j = 0; j < 10; ++j) { acc[i][j][0] = 0.f; acc[i][j][1] = 0.f; acc[i][j][2] = 0.f; acc[i][j][3] = 0.f; }

  {
    float2 af2[8];
#pragma unroll
    for (int p = 0; p < 8; ++p) af2[p] = asrc2[(chalf * 16 + 2 * p) >> 1];
    uint4 r0 = *(const uint4*)b0;
    uint4 r1 = *(const uint4*)b1;
    uint4 r2 = h2b ? *(const uint4*)b2 : uint4{0, 0, 0, 0};
    uint4 w0, w1;
    w0.x = packbf(af2[0]); w0.y = packbf(af2[1]); w0.z = packbf(af2[2]); w0.w = packbf(af2[3]);
    w1.x = packbf(af2[4]); w1.y = packbf(af2[5]); w1.z = packbf(af2[6]); w1.w = packbf(af2[7]);
    Ab[0][(chalf * 2 + 0) * 129 + rowA] = w0;
    Ab[0][(chalf * 2 + 1) * 129 + rowA] = w1;
    Bb[0][sub0 * 161 + rb0] = r0;
    Bb[0][sub1 * 161 + rb1] = r1;
    if (h2b) Bb[0][sub2 * 161 + rb2] = r2;
  }
  __syncthreads();

  for (int kb = 0; kb < 10; ++kb) {
    const int par = kb & 1;
    float2 af2[8];
    uint4 r0, r1, r2;
    if (kb < 9) {
      const int base = (kb + 1) * 32 + chalf * 16;
#pragma unroll
      for (int p = 0; p < 8; ++p) {
        int cc = base + 2 * p;
        if (cc < WE) af2[p] = asrc2[cc >> 1];
        else { af2[p].x = 0.f; af2[p].y = 0.f; }
      }
      const int ko = (kb + 1) * 32;
      r0 = *(const uint4*)(b0 + ko);
      r1 = *(const uint4*)(b1 + ko);
      if (h2b) r2 = *(const uint4*)(b2 + ko);
    }
    s16x8 fa0 = __builtin_bit_cast(s16x8, Ab[par][q4 * 129 + wave * 32 + mrow]);
    s16x8 fa1 = __builtin_bit_cast(s16x8, Ab[par][q4 * 129 + wave * 32 + 16 + mrow]);
#pragma unroll
    for (int ni = 0; ni < 10; ++ni) {
      s16x8 fb = __builtin_bit_cast(s16x8, Bb[par][q4 * 161 + ni * 16 + mrow]);
      acc[0][ni] = __builtin_amdgcn_mfma_f32_16x16x32_bf16(fa0, fb, acc[0][ni], 0, 0, 0);
      acc[1][ni] = __builtin_amdgcn_mfma_f32_16x16x32_bf16(fa1, fb, acc[1][ni], 0, 0, 0);
    }
    if (kb < 9) {
      uint4 w0, w1;
      w0.x = packbf(af2[0]); w0.y = packbf(af2[1]); w0.z = packbf(af2[2]); w0.w = packbf(af2[3]);
      w1.x = packbf(af2[4]); w1.y = packbf(af2[5]); w1.z = packbf(af2[6]); w1.w = packbf(af2[7]);
      Ab[par ^ 1][(chalf * 2 + 0) * 129 + rowA] = w0;
      Ab[par ^ 1][(chalf * 2 + 1) * 129 + rowA] = w1;
      Bb[par ^ 1][sub0 * 161 + rb0] = r0;
      Bb[par ^ 1][sub1 * 161 + rb1] = r1;
      if (h2b) Bb[par ^ 1][sub2 * 161 + rb2] = r2;
    }
    __syncthreads();
  }

#pragma unroll
  for (int mi = 0; mi < 2; ++mi) {
#pragma unroll
    for (int ni = 0; ni < 10; ++ni) {
      int col = nbase + ni * 16 + mrow;
      if (col < G4) {
        int orig = (col & 3) * 75 + (col >> 2);
        float bv = bvec[orig];
#pragma unroll
        for (int reg = 0; reg < 4; ++reg) {
          int m = mlo + wave * 32 + mi * 16 + q4 * 4 + reg;
          XWc[(size_t)m * G4 + col] = acc[mi][ni][reg] + bv;
        }
      }
    }
  }
}

// ---------------------------------------------------------------------------
// K2 REWRITE: MFMA batched-chain LSTM. One 512-thread (8-wave) block per
// segment; each block runs ALL 24 chains (t = timestep id) over its sample
// range. Per step: Z = U_perm (304x96, f16, in regs) @ H (32x96, f16, LDS,
// double-buffered)  via mfma_f32_16x16x32_f16; D row = U-col (gate-
// interleaved: row_local = 4*e_local + gate = (lane>>4)*4 + reg), D col = t
// (lane&15). So each lane's 4 acc regs = the 4 gates of one (t,e):
// activation is lane-local, XW add is one coalesced dwordx4, h is one
// ds_write_b16. LDS/step: 6 ds_read_b128 + 6 ds_write_b16 per wave.
// Rationale: rounds 2/4/5 proved old k_lstm was aggregate-throughput-bound
// (~1171 cyc/CU/block-step, time invariant to schedule), dominated by the
// per-thread h-broadcast (30KB LDS/block-step). This cuts work/step ~10x.
// ---------------------------------------------------------------------------
#define NTMAX 3

#define LSTM_STEP2(MM, BUF, XC)                                                        \
  {                                                                                    \
    const int mm = (MM);                                                               \
    f16x8 hf[2][3];                                                                    \
    _Pragma("unroll")                                                                  \
    for (int tt = 0; tt < 2; ++tt)                                                     \
      _Pragma("unroll")                                                                \
      for (int kg = 0; kg < 3; ++kg)                                                   \
        hf[tt][kg] = *(const f16x8*)&Hl[BUF][tt * 16 + lm][kg * 32 + lk * 8];          \
    f32x4 ac[NTMAX][2];                                                                \
    _Pragma("unroll")                                                                  \
    for (int i = 0; i < NTMAX; ++i) if (i < NT) {                                      \
      _Pragma("unroll")                                                                \
      for (int tt = 0; tt < 2; ++tt) {                                                 \
        f32x4 a = {0.f, 0.f, 0.f, 0.f};                                                \
        a = __builtin_amdgcn_mfma_f32_16x16x32_f16(u[i][0], hf[tt][0], a, 0, 0, 0);    \
        a = __builtin_amdgcn_mfma_f32_16x16x32_f16(u[i][1], hf[tt][1], a, 0, 0, 0);    \
        a = __builtin_amdgcn_mfma_f32_16x16x32_f16(u[i][2], hf[tt][2], a, 0, 0, 0);    \
        ac[i][tt] = a;                                                                 \
      }                                                                                \
    }                                                                                  \
    const int ng = gbase + mm;                                                         \
    const int bi = ng / 18;                                                            \
    const int rr = ng - bi * 18;                                                       \
    const bool win = (rr >= 12);                                                       \
    float aw = 0.f;                                                                    \
    if (win)                                                                           \
      aw = (rr == 12) ? aA[0] : (rr == 13) ? aA[1] : (rr == 14) ? aA[2]                \
         : (rr == 15) ? aA[3] : (rr == 16) ? aA[4] : aA[5];                            \
    const bool fl = (rr == 17) && (ng >= out_lo);                                      \
    const bool ldok = (mm + 2 < count);                                                \
    _Pragma("unroll")                                                                  \
    for (int i = 0; i < NTMAX; ++i) if (i < NT) {                                      \
      const int e = (w + 8 * i) * 4 + lk;                                              \
      _Pragma("unroll")                                                                \
      for (int tt = 0; tt < 2; ++tt) {                                                 \
        const int t = tt * 16 + lm;                                                    \
        const bool val = (t < 24) && (e < HL);                                         \
        f32x4 z4 = ac[i][tt] + XC[i][tt];                                              \
        if (ldok && val)                                                               \
          XC[i][tt] = *(const f32x4*)(XWc + ((size_t)(start + mm + 2) * 24 + t) * G4 + 4 * e); \
        float si = sigm(z4[0]);                                                        \
        float sf = sigm(z4[1]);                                                        \
        float tg = tanh_f(z4[2]);                                                      \
        float so = sigm(z4[3]);                                                        \
        float c = fmaf(sf, cst[i][tt], si * tg);                                       \
        cst[i][tt] = c;                                                                \
        float h = so * tanh_f(c);                                                      \
        hlv[i][tt] = h;                                                                \
        if (val) {                                                                     \
          _Float16 hh = (_Float16)h;                                                   \
          Hl[(BUF) ^ 1][t][e] = __builtin_bit_cast(unsigned short, hh);                \
        }                                                                              \
        if (win) {                                                                     \
          accA[i][tt] = fmaf(aw, h, accA[i][tt]);                                      \
          if (fl) {                                                                    \
            if (val) P[((size_t)((t << 8) + bi)) * 76 + e] = accA[i][tt];              \
            accA[i][tt] = 0.f;                                                         \
          }                                                                            \
        }                                                                              \
      }                                                                                \
    }                                                                                  \
    lds_barrier();                                                                     \
  }

__global__ __launch_bounds__(512) void k_lstm(const float* __restrict__ XWc,
                                              const unsigned short* __restrict__ Upp,
                                              const float* __restrict__ Atw,
                                              float* __restrict__ P,
                                              float* __restrict__ Sbuf,
                                              int n0, int S, int nseg,
                                              int first, int parity) {
  __shared__ __align__(16) unsigned short Hl[2][32][104];  // 13.3 KB, dbuf; row 208B (16B-mult, 8-bank spread)
  const int tid = threadIdx.x;
  const int w = tid >> 6, l = tid & 63;
  const int lm = l & 15;          // t within 16-tile; also B fragment row
  const int lk = l >> 4;          // 0..3: e_local; also k-subgroup
  const int seg = blockIdx.x;
  const int NT = (w < 3) ? 3 : 2; // M-tiles per wave: tiles {w, w+8, w+16(w<3)} cover 0..18

  const int start = seg * S - (seg ? LBI : 0);
  const int count = S + (seg ? LBI : 0);
  const int gbase = n0 + start;
  const int out_lo = n0 + seg * S;

  // U fragments in registers (constant across steps)
  f16x8 u[NTMAX][3];
#pragma unroll
  for (int i = 0; i < NTMAX; ++i) if (i < NT) {
    const int col = (w + 8 * i) * 16 + lm;   // <= 303
#pragma unroll
    for (int kg = 0; kg < 3; ++kg)
      u[i][kg] = __builtin_bit_cast(f16x8, *(const uint4*)(Upp + (size_t)col * 96 + kg * 32 + lk * 8));
  }

  float aA[6];
#pragma unroll
  for (int k = 0; k < 6; ++k) aA[k] = Atw[k];

  // zero both H buffers (incl. padding rows 24-31, cols 75-103)
  {
    unsigned* hz = (unsigned*)&Hl[0][0][0];
    for (int i = tid; i < 2 * 32 * 104 / 2; i += 512) hz[i] = 0;
  }

  float cst[NTMAX][2], hlv[NTMAX][2], accA[NTMAX][2];
#pragma unroll
  for (int i = 0; i < NTMAX; ++i)
#pragma unroll
    for (int tt = 0; tt < 2; ++tt) { cst[i][tt] = 0.f; hlv[i][tt] = 0.f; accA[i][tt] = 0.f; }

  __syncthreads();  // Hl zero visible

  if (seg == 0 && !first) {
#pragma unroll
    for (int i = 0; i < NTMAX; ++i) if (i < NT) {
      const int e = (w + 8 * i) * 4 + lk;
#pragma unroll
      for (int tt = 0; tt < 2; ++tt) {
        const int t = tt * 16 + lm;
        if (t < 24 && e < HL) {
          const float* Sp = Sbuf + (size_t)(parity * 24 + t) * 160;
          cst[i][tt] = Sp[e];
          float hv = Sp[80 + e];
          hlv[i][tt] = hv;
          _Float16 hh = (_Float16)hv;
          Hl[0][t][e] = __builtin_bit_cast(unsigned short, hh);
        }
      }
    }
  }

  // XW prefetch regs: XA = even steps, XB = odd steps (distance 2)
  f32x4 XA[NTMAX][2], XB[NTMAX][2];
#pragma unroll
  for (int i = 0; i < NTMAX; ++i)
#pragma unroll
    for (int tt = 0; tt < 2; ++tt) {
      XA[i][tt] = f32x4{0.f, 0.f, 0.f, 0.f};
      XB[i][tt] = f32x4{0.f, 0.f, 0.f, 0.f};
    }
#pragma unroll
  for (int i = 0; i < NTMAX; ++i) if (i < NT) {
    const int e = (w + 8 * i) * 4 + lk;
#pragma unroll
    for (int tt = 0; tt < 2; ++tt) {
      const int t = tt * 16 + lm;
      if (t < 24 && e < HL) {
        XA[i][tt] = *(const f32x4*)(XWc + ((size_t)(start + 0) * 24 + t) * G4 + 4 * e);
        XB[i][tt] = *(const f32x4*)(XWc + ((size_t)(start + 1) * 24 + t) * G4 + 4 * e);
      }
    }
  }
  __syncthreads();  // initial h (Sbuf case) visible

  for (int m = 0; m < count; m += 2) {
    LSTM_STEP2(m,     0, XA)
    LSTM_STEP2(m + 1, 1, XB)
  }

  if (seg == nseg - 1) {
#pragma unroll
    for (int i = 0; i < NTMAX; ++i) if (i < NT) {
      const int e = (w + 8 * i) * 4 + lk;
#pragma unroll
      for (int tt = 0; tt < 2; ++tt) {
        const int t = tt * 16 + lm;
        if (t < 24 && e < HL) {
          float* Sp = Sbuf + (size_t)((parity ^ 1) * 24 + t) * 160;
          Sp[e] = cst[i][tt];
          Sp[80 + e] = hlv[i][tt];
        }
      }
    }
  }
}

// ---------------------------------------------------------------------------
// K3: hA -> ctx (ut==2) -> xg = ctx@gru_W + gru_b[0]. grid 256, 320 thr.
// ---------------------------------------------------------------------------
__global__ __launch_bounds__(320) void k_ctx(const float* __restrict__ P,
                                             const float* __restrict__ Wtw,
                                             const float* __restrict__ btw,
                                             const float* __restrict__ Atw,
                                             const float* __restrict__ Btw,
                                             const float* __restrict__ X,
                                             const float* __restrict__ Wg,
                                             const float* __restrict__ bg,
                                             float* __restrict__ xg) {
  __shared__ float hA[76];
  __shared__ float ctx[312];
  const int b = blockIdx.x, j = threadIdx.x;
  if (j < HL) {
    float s = 0.f;
    for (int t = 0; t < SLEN; ++t) s += P[((t << 8) + b) * 76 + j];
    hA[j] = s * (1.0f / 24.0f);
  }
  __syncthreads();
  if (j < G4) {
    float SA = Atw[0] + Atw[1] + Atw[2] + Atw[3] + Atw[4] + Atw[5];
    float s = SA * btw[j];
    for (int k = 0; k < HL; ++k) s = fmaf(hA[k], Wtw[k * G4 + j], s);
    ctx[j] = s * (1000.0f / 1001.0f) + Btw[0];
  } else if (j < 310) {
    int f = j - G4;
    float s = 0.f;
#pragma unroll
    for (int nt = 0; nt < 6; ++nt)
      s = fmaf(Atw[nt], X[(size_t)((b * 3 + 2) * 6 + nt) * DIN + 7200 + f], s);
    ctx[j] = s * (1.0f / 1001.0f) + Btw[0];
  }
  __syncthreads();
  if (j < G3) {
    float s = bg[j];
    for (int f = 0; f < 310; ++f) s = fmaf(ctx[f], Wg[f * G3 + j], s);
    xg[b * 240 + j] = s;
  }
}

// ---------------------------------------------------------------------------
// K5: segmented GRU (chain ut==2). grid 16 blocks x 256 thr.
// ---------------------------------------------------------------------------
#define GRU_STEP(B, PF)                                                                \
  {                                                                                    \
    if (q < G3) {                                                                      \
      const float4* h4 = (const float4*)gh;                                            \
      float a0 = b1, a1 = 0.f, a2 = 0.f, a3 = 0.f;                                     \
      _Pragma("unroll")                                                                \
      for (int p = 0; p < 20; ++p) {                                                   \
        float4 hv = h4[p];                                                             \
        a0 = fmaf(ug[4 * p + 0], hv.x, a0);                                            \
        a1 = fmaf(ug[4 * p + 1], hv.y, a1);                                            \
        a2 = fmaf(ug[4 * p + 2], hv.z, a2);                                            \
        a3 = fmaf(ug[4 * p + 3], hv.w, a3);                                            \
      }                                                                                \
      float rs = (a0 + a1) + (a2 + a3);                                                \
      float pnew = ((B) + 2 < 256) ? xg[((B) + 2) * 240 + q] : 0.f;                    \
      if (q < HG) {                                                                    \
        zreg = sigm((PF) + rs);                                                        \
      } else if (q < 154) {                                                            \
        rbuf[q - 77] = sigm((PF) + rs);                                                \
      } else {                                                                         \
        xkeep = (PF);                                                                  \
        rkeep = rs;                                                                    \
      }                                                                                \
      (PF) = pnew;                                                                     \
    }                                                                                  \
    lds_barrier();                                                                     \
    if (q >= 154 && q < G3) hhb[q - 154] = tanh_f(xkeep + rbuf[q - 154] * rkeep);      \
    lds_barrier();                                                                     \
    if (q < HG) {                                                                      \
      float hh = hhb[q];                                                               \
      hq = zreg * hq + (1.0f - zreg) * hh;                                             \
      gh[q] = hq;                                                                      \
      if ((B) >= out_lo) Hg[(B) * 80 + q] = hq;                                        \
    }                                                                                  \
    lds_barrier();                                                                     \
  }

__global__ __launch_bounds__(256) void k_gru(const float* __restrict__ Ug,
                                             const float* __restrict__ bg,
                                             const float* __restrict__ xg,
                                             float* __restrict__ Hg) {
  __shared__ __align__(16) float gh[80];
  __shared__ float rbuf[77];
  __shared__ float hhb[77];
  const int q = threadIdx.x;
  const int b0 = blockIdx.x;
  const int out_lo = b0 * 16;
  const int start = b0 ? (out_lo - 16) : 0;
  const int end = out_lo + 16;
  float ug[80];
  float b1 = 0.f;
  if (q < G3) {
    b1 = bg[G3 + q];
#pragma unroll
    for (int k = 0; k < 80; ++k) ug[k] = (k < HG) ? Ug[k * G3 + q] : 0.f;
  }
  if (q < 80) gh[q] = 0.f;
  float hq = 0.f, zreg = 0.f, xkeep = 0.f, rkeep = 0.f;
  float pf0 = (q < G3) ? xg[start * 240 + q] : 0.f;
  float pf1 = (q < G3) ? xg[(start + 1) * 240 + q] : 0.f;
  __syncthreads();
  for (int b = start; b < end; b += 2) {
    GRU_STEP(b, pf0)
    GRU_STEP(b + 1, pf1)
  }
}

// ---------------------------------------------------------------------------
__global__ __launch_bounds__(64) void k_out(const float* __restrict__ Hg,
                                            const float* __restrict__ Wl,
                                            const float* __restrict__ bl,
                                            float* __restrict__ out) {
  __shared__ float lb[CLS];
  __shared__ float eb[CLS];
  const int b = blockIdx.x, j = threadIdx.x;
  float lg = 0.f;
  if (j < CLS) {
    lg = bl[j];
    for (int k = 0; k < HG; ++k) lg = fmaf(Hg[b * 80 + k], Wl[k * CLS + j], lg);
    lb[j] = lg;
  }
  __syncthreads();
  float ex = 0.f;
  if (j < CLS) {
    float m = lb[0];
    for (int i = 1; i < CLS; ++i) m = fmaxf(m, lb[i]);
    ex = fast_exp2((lg - m) * 1.4426950408889634f);
    eb[j] = ex;
  }
  __syncthreads();
  if (j < CLS) {
    float s = 0.f;
    for (int i = 0; i < CLS; ++i) s += eb[i];
    out[b * CLS + j] = ex / s;
  }
}

// ---------------------------------------------------------------------------
extern "C" void kernel_launch(void* const* d_in, const int* in_sizes, int n_in,
                              void* d_out, int out_size, void* d_ws, size_t ws_size,
                              hipStream_t stream) {
  const float* X    = (const float*)d_in[0];
  const float* lW   = (const float*)d_in[1];
  const float* lU   = (const float*)d_in[2];
  const float* lb   = (const float*)d_in[3];
  const float* twW  = (const float*)d_in[4];
  const float* twb  = (const float*)d_in[5];
  const float* Atw  = (const float*)d_in[6];
  const float* Btw  = (const float*)d_in[7];
  const float* gW   = (const float*)d_in[8];
  const float* gU   = (const float*)d_in[9];
  const float* gb   = (const float*)d_in[10];
  const float* linW = (const float*)d_in[11];
  const float* linb = (const float*)d_in[12];
  float* out = (float*)d_out;

  char* ws = (char*)d_ws;
  unsigned short* Wt = (unsigned short*)(ws + 0);        // 204800
  unsigned short* Up = (unsigned short*)(ws + 204800);   // 58368 (304x96 f16)
  float* P   = (float*)(ws + 263168);                    // 1867776
  float* Sb  = (float*)(ws + 2130944);                   // 30720
  float* xg  = (float*)(ws + 2161664);                   // 245760
  float* Hg  = (float*)(ws + 2407424);                   // 81920
  float* XWc = (float*)(ws + 2489344);                   // NC*24*300*4 (full: 132.7 MB)

  const size_t fixed = 2489344;
  int NC = 144;
  for (int k : {32, 16, 8, 4, 2, 1}) {
    size_t need = fixed + (size_t)144 * k * 28800;
    if (need <= ws_size) { NC = 144 * k; break; }
  }
  const int chunks = NSTEP / NC;
  // Segmentation for the MFMA k_lstm: one block per segment, <=256 blocks
  // (1 block/CU). S multiple of 6 preserves the verified burn-in modular
  // guarantees. NC=4608 -> S=48, nseg=96, 64 steps/block.
  int S = NC, nseg = 1;
  for (int s : {48, 96, 192, 288, 576}) {
    if (NC % s == 0 && NC / s <= 256) { S = s; nseg = NC / s; break; }
  }

  k_prep_wt<<<dim3(400), dim3(256), 0, stream>>>(lW, Wt);
  k_prep_u<<<dim3(114), dim3(256), 0, stream>>>(lU, Up);
  for (int ci = 0; ci < chunks; ++ci) {
    const int n0 = ci * NC;
    k_gemm<<<dim3(NC * 24 / 128, 2), dim3(256), 0, stream>>>(X, Wt, lb, XWc, n0);
    k_lstm<<<dim3(nseg), dim3(512), 0, stream>>>(XWc, Up, Atw, P, Sb,
                                                 n0, S, nseg,
                                                 ci == 0 ? 1 : 0, ci & 1);
  }
  k_ctx<<<dim3(256), dim3(320), 0, stream>>>(P, twW, twb, Atw, Btw, X, gW, gb, xg);
  k_gru<<<dim3(16), dim3(256), 0, stream>>>(gU, gb, xg, Hg);
  k_out<<<dim3(256), dim3(64), 0, stream>>>(Hg, linW, linb, out);
}

// Round 7
// 387.841 us; speedup vs baseline: 1.5538x; 1.1553x over previous
//
#include <hip/hip_runtime.h>
#include <hip/hip_bf16.h>
#include <cstdint>
#include <cstddef>
#include <initializer_list>

// Problem constants
#define WE    300
#define TEF   10
#define SLEN  24
#define HL    75      // H_LSTM
#define G4    300     // 4*HL
#define HG    77      // H_GRU
#define G3    231     // 3*HG
#define CLS   27
#define DIN   7210
#define NSTEP 4608
#define LBI   16      // LSTM segment burn-in (first emitted window gets >=28 warm steps at S=18)

typedef short    s16x8 __attribute__((ext_vector_type(8)));
typedef float    f32x4 __attribute__((ext_vector_type(4)));
typedef _Float16 f16x8 __attribute__((ext_vector_type(8)));

static __device__ __forceinline__ unsigned short f2bf(float f) {
  unsigned u = __builtin_bit_cast(unsigned, f);
  unsigned r = u + 0x7fffu + ((u >> 16) & 1u);   // RNE
  return (unsigned short)(r >> 16);
}
static __device__ __forceinline__ unsigned packbf(float2 v) {
  return (unsigned)f2bf(v.x) | ((unsigned)f2bf(v.y) << 16);
}

static __device__ __forceinline__ float fast_exp2(float x) {
#if __has_builtin(__builtin_amdgcn_exp2f)
  return __builtin_amdgcn_exp2f(x);
#else
  return __exp2f(x);
#endif
}
static __device__ __forceinline__ float fast_rcp(float x) {
#if __has_builtin(__builtin_amdgcn_rcpf)
  return __builtin_amdgcn_rcpf(x);
#else
  return 1.0f / x;
#endif
}
static __device__ __forceinline__ float sigm(float x) {
  return fast_rcp(1.0f + fast_exp2(-1.4426950408889634f * x));
}
static __device__ __forceinline__ float tanh_f(float x) {
  return 2.0f * fast_rcp(1.0f + fast_exp2(-2.8853900817779268f * x)) - 1.0f;
}

// LDS-only barrier (global prefetch stays in flight)
static __device__ __forceinline__ void lds_barrier() {
  __asm__ volatile("s_waitcnt lgkmcnt(0)\n\ts_barrier" ::: "memory");
}

// ---------------------------------------------------------------------------
// Wt2 K-TILED: Wt2[kb][n][kk] = lstm_W[kb*32+kk][orig(n)], bf16, [10][320][32].
// Column permutation n = 4*e + gate (orig = gate*75+e) as in round 6.
// K-tiling makes k_gemm's B staging lane-contiguous (16B/lane, coalesced)
// instead of 64 strided-row transactions per load instruction.
// ---------------------------------------------------------------------------
__global__ __launch_bounds__(256) void k_prep_wt(const float* __restrict__ W,
                                                 unsigned short* __restrict__ Wt2) {
  int idx = blockIdx.x * 256 + threadIdx.x;
  if (idx >= 320 * 320) return;
  int n = idx / 320, k = idx - n * 320;
  float v = 0.0f;
  if (n < G4 && k < WE) {
    int e = n >> 2, g = n & 3;
    v = W[k * G4 + (g * 75 + e)];
  }
  size_t dst = ((size_t)(k >> 5) * 320 + n) * 32 + (k & 31);
  Wt2[dst] = f2bf(v);
}

// Upp[c][k] f16, [304][96]: Upp[c][k] = lstm_U[k][orig(c)], zero-padded.
__global__ __launch_bounds__(256) void k_prep_u(const float* __restrict__ U,
                                                unsigned short* __restrict__ Upp) {
  int idx = blockIdx.x * 256 + threadIdx.x;
  if (idx >= 304 * 96) return;
  int c = idx / 96, k = idx - c * 96;
  float v = 0.f;
  int e = c >> 2, g = c & 3;
  if (e < HL && k < HL) v = U[k * G4 + g * 75 + e];
  _Float16 hv = (_Float16)v;
  Upp[idx] = __builtin_bit_cast(unsigned short, hv);
}

// ---------------------------------------------------------------------------
// K1 v2: XWc = we @ lstm_W + lstm_b (permuted cols). 512 threads / 8 waves,
// wave w owns rows [w*16, w*16+16) -> acc[10] = 40 AGPR/thread (was 80):
// unified reg budget ~110 -> 2 blocks/CU (16 waves, ~50% occ) vs r6's 184 ->
// 20.8%. B staging from k-tiled Wt2: slab (kb, nbase) is contiguous; thread
// loads 16B at o=tid (and tid+512<640) -> fully coalesced. A staging spread
// over 512 threads (4x float2 + 4 pack each). LDS layout + MFMA fragment
// indexing identical to the r6-verified kernel -> bit-identical output.
// grid (NC*24/128, 2).
// ---------------------------------------------------------------------------
__global__ __launch_bounds__(512) void k_gemm(const float* __restrict__ X,
                                              const unsigned short* __restrict__ Wt2,
                                              const float* __restrict__ bvec,
                                              float* __restrict__ XWc, int n0) {
  __shared__ __align__(16) uint4 Ab[2][516];   // 4 kgroups x (128+1) rows
  __shared__ __align__(16) uint4 Bb[2][648];   // 4 kgroups x (160+1) rows
  const int tid = threadIdx.x;
  const int wave = tid >> 6, lane = tid & 63;
  const int mlo = blockIdx.x * 128;
  const int nbase = blockIdx.y * 160;
  const int mrow = lane & 15, q4 = lane >> 4;

  // A staging: thread covers row rowA (0..127), bf16-cols [kb*32+qtr*8, +8)
  const int rowA = tid >> 2, qtr = tid & 3;
  const int mg = n0 * 24 + mlo + rowA;
  const int an = mg / 24, at = mg - an * 24;
  const float2* asrc2 = (const float2*)(X + (size_t)an * DIN + at * WE);  // 8B-aligned

  // B staging: 16B chunk o of the 640-chunk slab [kb][nbase..nbase+160][32]
  const int o0 = tid, o1 = tid + 512;
  const bool h1 = (tid < 128);
  const unsigned short* bsrc = Wt2 + (size_t)nbase * 32;   // + kb*10240 per kb

  f32x4 acc[10];
#pragma unroll
  for (int j = 0; j < 10; ++j) { acc[j][0] = 0.f; acc[j][1] = 0.f; acc[j][2] = 0.f; acc[j][3] = 0.f; }

  // prologue: stage kb=0 into buf 0
  {
    float2 af2[4];
#pragma unroll
    for (int p = 0; p < 4; ++p) af2[p] = asrc2[(qtr * 8 + 2 * p) >> 1];  // cols <= 30 < 300
    uint4 r0 = *(const uint4*)(bsrc + (size_t)o0 * 8);
    uint4 r1 = h1 ? *(const uint4*)(bsrc + (size_t)o1 * 8) : uint4{0, 0, 0, 0};
    uint4 w0;
    w0.x = packbf(af2[0]); w0.y = packbf(af2[1]); w0.z = packbf(af2[2]); w0.w = packbf(af2[3]);
    Ab[0][qtr * 129 + rowA] = w0;
    Bb[0][(o0 & 3) * 161 + (o0 >> 2)] = r0;
    if (h1) Bb[0][(o1 & 3) * 161 + (o1 >> 2)] = r1;
  }
  __syncthreads();

  for (int kb = 0; kb < 10; ++kb) {
    const int par = kb & 1;
    float2 af2[4];
    uint4 r0, r1;
    if (kb < 9) {
      const int base = (kb + 1) * 32 + qtr * 8;
#pragma unroll
      for (int p = 0; p < 4; ++p) {
        int cc = base + 2 * p;
        if (cc < WE) af2[p] = asrc2[cc >> 1];
        else { af2[p].x = 0.f; af2[p].y = 0.f; }
      }
      const unsigned short* bk = bsrc + (size_t)(kb + 1) * 10240;  // 320*32
      r0 = *(const uint4*)(bk + (size_t)o0 * 8);
      if (h1) r1 = *(const uint4*)(bk + (size_t)o1 * 8);
    }
    s16x8 fa = __builtin_bit_cast(s16x8, Ab[par][q4 * 129 + wave * 16 + mrow]);
#pragma unroll
    for (int ni = 0; ni < 10; ++ni) {
      s16x8 fb = __builtin_bit_cast(s16x8, Bb[par][q4 * 161 + ni * 16 + mrow]);
      acc[ni] = __builtin_amdgcn_mfma_f32_16x16x32_bf16(fa, fb, acc[ni], 0, 0, 0);
    }
    if (kb < 9) {
      uint4 w0;
      w0.x = packbf(af2[0]); w0.y = packbf(af2[1]); w0.z = packbf(af2[2]); w0.w = packbf(af2[3]);
      Ab[par ^ 1][qtr * 129 + rowA] = w0;
      Bb[par ^ 1][(o0 & 3) * 161 + (o0 >> 2)] = r0;
      if (h1) Bb[par ^ 1][(o1 & 3) * 161 + (o1 >> 2)] = r1;
    }
    __syncthreads();
  }

  // epilogue: C layout col=lane&15, row=(lane>>4)*4+reg; bias via orig(col)
#pragma unroll
  for (int ni = 0; ni < 10; ++ni) {
    int col = nbase + ni * 16 + mrow;
    if (col < G4) {
      int orig = (col & 3) * 75 + (col >> 2);
      float bv = bvec[orig];
#pragma unroll
      for (int reg = 0; reg < 4; ++reg) {
        int m = mlo + wave * 16 + q4 * 4 + reg;
        XWc[(size_t)m * G4 + col] = acc[ni][reg] + bv;
      }
    }
  }
}

// ---------------------------------------------------------------------------
// K2: MFMA batched-chain LSTM (r6-verified). One 512-thread block per
// segment, all 24 chains per block. Z = U_perm(304x96 f16, regs) @ H(32x96
// f16, LDS dbuf) via mfma_f32_16x16x32_f16; activation lane-local via the
// gate-interleaved column permutation. r7: S=18 -> nseg=256 (all CUs),
// 34 serial steps vs 64.
// ---------------------------------------------------------------------------
#define NTMAX 3

#define LSTM_STEP2(MM, BUF, XC)                                                        \
  {                                                                                    \
    const int mm = (MM);                                                               \
    f16x8 hf[2][3];                                                                    \
    _Pragma("unroll")                                                                  \
    for (int tt = 0; tt < 2; ++tt)                                                     \
      _Pragma("unroll")                                                                \
      for (int kg = 0; kg < 3; ++kg)                                                   \
        hf[tt][kg] = *(const f16x8*)&Hl[BUF][tt * 16 + lm][kg * 32 + lk * 8];          \
    f32x4 ac[NTMAX][2];                                                                \
    _Pragma("unroll")                                                                  \
    for (int i = 0; i < NTMAX; ++i) if (i < NT) {                                      \
      _Pragma("unroll")                                                                \
      for (int tt = 0; tt < 2; ++tt) {                                                 \
        f32x4 a = {0.f, 0.f, 0.f, 0.f};                                                \
        a = __builtin_amdgcn_mfma_f32_16x16x32_f16(u[i][0], hf[tt][0], a, 0, 0, 0);    \
        a = __builtin_amdgcn_mfma_f32_16x16x32_f16(u[i][1], hf[tt][1], a, 0, 0, 0);    \
        a = __builtin_amdgcn_mfma_f32_16x16x32_f16(u[i][2], hf[tt][2], a, 0, 0, 0);    \
        ac[i][tt] = a;                                                                 \
      }                                                                                \
    }                                                                                  \
    const int ng = gbase + mm;                                                         \
    const int bi = ng / 18;                                                            \
    const int rr = ng - bi * 18;                                                       \
    const bool win = (rr >= 12);                                                       \
    float aw = 0.f;                                                                    \
    if (win)                                                                           \
      aw = (rr == 12) ? aA[0] : (rr == 13) ? aA[1] : (rr == 14) ? aA[2]                \
         : (rr == 15) ? aA[3] : (rr == 16) ? aA[4] : aA[5];                            \
    const bool fl = (rr == 17) && (ng >= out_lo);                                      \
    const bool ldok = (mm + 2 < count);                                                \
    _Pragma("unroll")                                                                  \
    for (int i = 0; i < NTMAX; ++i) if (i < NT) {                                      \
      const int e = (w + 8 * i) * 4 + lk;                                              \
      _Pragma("unroll")                                                                \
      for (int tt = 0; tt < 2; ++tt) {                                                 \
        const int t = tt * 16 + lm;                                                    \
        const bool val = (t < 24) && (e < HL);                                         \
        f32x4 z4 = ac[i][tt] + XC[i][tt];                                              \
        if (ldok && val)                                                               \
          XC[i][tt] = *(const f32x4*)(XWc + ((size_t)(start + mm + 2) * 24 + t) * G4 + 4 * e); \
        float si = sigm(z4[0]);                                                        \
        float sf = sigm(z4[1]);                                                        \
        float tg = tanh_f(z4[2]);                                                      \
        float so = sigm(z4[3]);                                                        \
        float c = fmaf(sf, cst[i][tt], si * tg);                                       \
        cst[i][tt] = c;                                                                \
        float h = so * tanh_f(c);                                                      \
        hlv[i][tt] = h;                                                                \
        if (val) {                                                                     \
          _Float16 hh = (_Float16)h;                                                   \
          Hl[(BUF) ^ 1][t][e] = __builtin_bit_cast(unsigned short, hh);                \
        }                                                                              \
        if (win) {                                                                     \
          accA[i][tt] = fmaf(aw, h, accA[i][tt]);                                      \
          if (fl) {                                                                    \
            if (val) P[((size_t)((t << 8) + bi)) * 76 + e] = accA[i][tt];              \
            accA[i][tt] = 0.f;                                                         \
          }                                                                            \
        }                                                                              \
      }                                                                                \
    }                                                                                  \
    lds_barrier();                                                                     \
  }

__global__ __launch_bounds__(512) void k_lstm(const float* __restrict__ XWc,
                                              const unsigned short* __restrict__ Upp,
                                              const float* __restrict__ Atw,
                                              float* __restrict__ P,
                                              float* __restrict__ Sbuf,
                                              int n0, int S, int nseg,
                                              int first, int parity) {
  __shared__ __align__(16) unsigned short Hl[2][32][104];  // 13.3 KB, dbuf
  const int tid = threadIdx.x;
  const int w = tid >> 6, l = tid & 63;
  const int lm = l & 15;          // t within 16-tile; B fragment row
  const int lk = l >> 4;          // 0..3: e_local; k-subgroup
  const int seg = blockIdx.x;
  const int NT = (w < 3) ? 3 : 2; // M-tiles {w, w+8, w+16(w<3)} cover 0..18

  const int start = seg * S - (seg ? LBI : 0);
  const int count = S + (seg ? LBI : 0);
  const int gbase = n0 + start;
  const int out_lo = n0 + seg * S;

  f16x8 u[NTMAX][3];
#pragma unroll
  for (int i = 0; i < NTMAX; ++i) if (i < NT) {
    const int col = (w + 8 * i) * 16 + lm;   // <= 303
#pragma unroll
    for (int kg = 0; kg < 3; ++kg)
      u[i][kg] = __builtin_bit_cast(f16x8, *(const uint4*)(Upp + (size_t)col * 96 + kg * 32 + lk * 8));
  }

  float aA[6];
#pragma unroll
  for (int k = 0; k < 6; ++k) aA[k] = Atw[k];

  {
    unsigned* hz = (unsigned*)&Hl[0][0][0];
    for (int i = tid; i < 2 * 32 * 104 / 2; i += 512) hz[i] = 0;
  }

  float cst[NTMAX][2], hlv[NTMAX][2], accA[NTMAX][2];
#pragma unroll
  for (int i = 0; i < NTMAX; ++i)
#pragma unroll
    for (int tt = 0; tt < 2; ++tt) { cst[i][tt] = 0.f; hlv[i][tt] = 0.f; accA[i][tt] = 0.f; }

  __syncthreads();  // Hl zero visible

  if (seg == 0 && !first) {
#pragma unroll
    for (int i = 0; i < NTMAX; ++i) if (i < NT) {
      const int e = (w + 8 * i) * 4 + lk;
#pragma unroll
      for (int tt = 0; tt < 2; ++tt) {
        const int t = tt * 16 + lm;
        if (t < 24 && e < HL) {
          const float* Sp = Sbuf + (size_t)(parity * 24 + t) * 160;
          cst[i][tt] = Sp[e];
          float hv = Sp[80 + e];
          hlv[i][tt] = hv;
          _Float16 hh = (_Float16)hv;
          Hl[0][t][e] = __builtin_bit_cast(unsigned short, hh);
        }
      }
    }
  }

  f32x4 XA[NTMAX][2], XB[NTMAX][2];
#pragma unroll
  for (int i = 0; i < NTMAX; ++i)
#pragma unroll
    for (int tt = 0; tt < 2; ++tt) {
      XA[i][tt] = f32x4{0.f, 0.f, 0.f, 0.f};
      XB[i][tt] = f32x4{0.f, 0.f, 0.f, 0.f};
    }
#pragma unroll
  for (int i = 0; i < NTMAX; ++i) if (i < NT) {
    const int e = (w + 8 * i) * 4 + lk;
#pragma unroll
    for (int tt = 0; tt < 2; ++tt) {
      const int t = tt * 16 + lm;
      if (t < 24 && e < HL) {
        XA[i][tt] = *(const f32x4*)(XWc + ((size_t)(start + 0) * 24 + t) * G4 + 4 * e);
        XB[i][tt] = *(const f32x4*)(XWc + ((size_t)(start + 1) * 24 + t) * G4 + 4 * e);
      }
    }
  }
  __syncthreads();  // initial h visible

  for (int m = 0; m < count; m += 2) {
    LSTM_STEP2(m,     0, XA)
    LSTM_STEP2(m + 1, 1, XB)
  }

  if (seg == nseg - 1) {
#pragma unroll
    for (int i = 0; i < NTMAX; ++i) if (i < NT) {
      const int e = (w + 8 * i) * 4 + lk;
#pragma unroll
      for (int tt = 0; tt < 2; ++tt) {
        const int t = tt * 16 + lm;
        if (t < 24 && e < HL) {
          float* Sp = Sbuf + (size_t)((parity ^ 1) * 24 + t) * 160;
          Sp[e] = cst[i][tt];
          Sp[80 + e] = hlv[i][tt];
        }
      }
    }
  }
}

// ---------------------------------------------------------------------------
// K3: hA -> ctx (ut==2) -> xg = ctx@gru_W + gru_b[0]. grid 256, 320 thr.
// ---------------------------------------------------------------------------
__global__ __launch_bounds__(320) void k_ctx(const float* __restrict__ P,
                                             const float* __restrict__ Wtw,
                                             const float* __restrict__ btw,
                                             const float* __restrict__ Atw,
                                             const float* __restrict__ Btw,
                                             const float* __restrict__ X,
                                             const float* __restrict__ Wg,
                                             const float* __restrict__ bg,
                                             float* __restrict__ xg) {
  __shared__ float hA[76];
  __shared__ float ctx[312];
  const int b = blockIdx.x, j = threadIdx.x;
  if (j < HL) {
    float s = 0.f;
    for (int t = 0; t < SLEN; ++t) s += P[((t << 8) + b) * 76 + j];
    hA[j] = s * (1.0f / 24.0f);
  }
  __syncthreads();
  if (j < G4) {
    float SA = Atw[0] + Atw[1] + Atw[2] + Atw[3] + Atw[4] + Atw[5];
    float s = SA * btw[j];
    for (int k = 0; k < HL; ++k) s = fmaf(hA[k], Wtw[k * G4 + j], s);
    ctx[j] = s * (1000.0f / 1001.0f) + Btw[0];
  } else if (j < 310) {
    int f = j - G4;
    float s = 0.f;
#pragma unroll
    for (int nt = 0; nt < 6; ++nt)
      s = fmaf(Atw[nt], X[(size_t)((b * 3 + 2) * 6 + nt) * DIN + 7200 + f], s);
    ctx[j] = s * (1.0f / 1001.0f) + Btw[0];
  }
  __syncthreads();
  if (j < G3) {
    float s = bg[j];
    for (int f = 0; f < 310; ++f) s = fmaf(ctx[f], Wg[f * G3 + j], s);
    xg[b * 240 + j] = s;
  }
}

// ---------------------------------------------------------------------------
// K5: segmented GRU (chain ut==2). grid 16 blocks x 256 thr.
// ---------------------------------------------------------------------------
#define GRU_STEP(B, PF)                                                                \
  {                                                                                    \
    if (q < G3) {                                                                      \
      const float4* h4 = (const float4*)gh;                                            \
      float a0 = b1, a1 = 0.f, a2 = 0.f, a3 = 0.f;                                     \
      _Pragma("unroll")                                                                \
      for (int p = 0; p < 20; ++p) {                                                   \
        float4 hv = h4[p];                                                             \
        a0 = fmaf(ug[4 * p + 0], hv.x, a0);                                            \
        a1 = fmaf(ug[4 * p + 1], hv.y, a1);                                            \
        a2 = fmaf(ug[4 * p + 2], hv.z, a2);                                            \
        a3 = fmaf(ug[4 * p + 3], hv.w, a3);                                            \
      }                                                                                \
      float rs = (a0 + a1) + (a2 + a3);                                                \
      float pnew = ((B) + 2 < 256) ? xg[((B) + 2) * 240 + q] : 0.f;                    \
      if (q < HG) {                                                                    \
        zreg = sigm((PF) + rs);                                                        \
      } else if (q < 154) {                                                            \
        rbuf[q - 77] = sigm((PF) + rs);                                                \
      } else {                                                                         \
        xkeep = (PF);                                                                  \
        rkeep = rs;                                                                    \
      }                                                                                \
      (PF) = pnew;                                                                     \
    }                                                                                  \
    lds_barrier();                                                                     \
    if (q >= 154 && q < G3) hhb[q - 154] = tanh_f(xkeep + rbuf[q - 154] * rkeep);      \
    lds_barrier();                                                                     \
    if (q < HG) {                                                                      \
      float hh = hhb[q];                                                               \
      hq = zreg * hq + (1.0f - zreg) * hh;                                             \
      gh[q] = hq;                                                                      \
      if ((B) >= out_lo) Hg[(B) * 80 + q] = hq;                                        \
    }                                                                                  \
    lds_barrier();                                                                     \
  }

__global__ __launch_bounds__(256) void k_gru(const float* __restrict__ Ug,
                                             const float* __restrict__ bg,
                                             const float* __restrict__ xg,
                                             float* __restrict__ Hg) {
  __shared__ __align__(16) float gh[80];
  __shared__ float rbuf[77];
  __shared__ float hhb[77];
  const int q = threadIdx.x;
  const int b0 = blockIdx.x;
  const int out_lo = b0 * 16;
  const int start = b0 ? (out_lo - 16) : 0;
  const int end = out_lo + 16;
  float ug[80];
  float b1 = 0.f;
  if (q < G3) {
    b1 = bg[G3 + q];
#pragma unroll
    for (int k = 0; k < 80; ++k) ug[k] = (k < HG) ? Ug[k * G3 + q] : 0.f;
  }
  if (q < 80) gh[q] = 0.f;
  float hq = 0.f, zreg = 0.f, xkeep = 0.f, rkeep = 0.f;
  float pf0 = (q < G3) ? xg[start * 240 + q] : 0.f;
  float pf1 = (q < G3) ? xg[(start + 1) * 240 + q] : 0.f;
  __syncthreads();
  for (int b = start; b < end; b += 2) {
    GRU_STEP(b, pf0)
    GRU_STEP(b + 1, pf1)
  }
}

// ---------------------------------------------------------------------------
__global__ __launch_bounds__(64) void k_out(const float* __restrict__ Hg,
                                            const float* __restrict__ Wl,
                                            const float* __restrict__ bl,
                                            float* __restrict__ out) {
  __shared__ float lb[CLS];
  __shared__ float eb[CLS];
  const int b = blockIdx.x, j = threadIdx.x;
  float lg = 0.f;
  if (j < CLS) {
    lg = bl[j];
    for (int k = 0; k < HG; ++k) lg = fmaf(Hg[b * 80 + k], Wl[k * CLS + j], lg);
    lb[j] = lg;
  }
  __syncthreads();
  float ex = 0.f;
  if (j < CLS) {
    float m = lb[0];
    for (int i = 1; i < CLS; ++i) m = fmaxf(m, lb[i]);
    ex = fast_exp2((lg - m) * 1.4426950408889634f);
    eb[j] = ex;
  }
  __syncthreads();
  if (j < CLS) {
    float s = 0.f;
    for (int i = 0; i < CLS; ++i) s += eb[i];
    out[b * CLS + j] = ex / s;
  }
}

// ---------------------------------------------------------------------------
extern "C" void kernel_launch(void* const* d_in, const int* in_sizes, int n_in,
                              void* d_out, int out_size, void* d_ws, size_t ws_size,
                              hipStream_t stream) {
  const float* X    = (const float*)d_in[0];
  const float* lW   = (const float*)d_in[1];
  const float* lU   = (const float*)d_in[2];
  const float* lb   = (const float*)d_in[3];
  const float* twW  = (const float*)d_in[4];
  const float* twb  = (const float*)d_in[5];
  const float* Atw  = (const float*)d_in[6];
  const float* Btw  = (const float*)d_in[7];
  const float* gW   = (const float*)d_in[8];
  const float* gU   = (const float*)d_in[9];
  const float* gb   = (const float*)d_in[10];
  const float* linW = (const float*)d_in[11];
  const float* linb = (const float*)d_in[12];
  float* out = (float*)d_out;

  char* ws = (char*)d_ws;
  unsigned short* Wt = (unsigned short*)(ws + 0);        // 204800 (k-tiled [10][320][32])
  unsigned short* Up = (unsigned short*)(ws + 204800);   // 58368 (304x96 f16)
  float* P   = (float*)(ws + 263168);                    // 1867776
  float* Sb  = (float*)(ws + 2130944);                   // 30720
  float* xg  = (float*)(ws + 2161664);                   // 245760
  float* Hg  = (float*)(ws + 2407424);                   // 81920
  float* XWc = (float*)(ws + 2489344);                   // NC*24*300*4 (full: 132.7 MB)

  const size_t fixed = 2489344;
  int NC = 144;
  for (int k : {32, 16, 8, 4, 2, 1}) {
    size_t need = fixed + (size_t)144 * k * 28800;
    if (need <= ws_size) { NC = 144 * k; break; }
  }
  const int chunks = NSTEP / NC;
  // S=18: one 18-window per segment, nseg = NC/18 <= 256 (all CUs), 34
  // serial steps (16 burn-in + 18). Burn-in guarantee unchanged (>=28 warm
  // steps before first accumulated h).
  int S = NC, nseg = 1;
  for (int s : {18, 24, 48, 96, 192, 288, 576}) {
    if (NC % s == 0 && NC / s <= 256) { S = s; nseg = NC / s; break; }
  }

  k_prep_wt<<<dim3(400), dim3(256), 0, stream>>>(lW, Wt);
  k_prep_u<<<dim3(114), dim3(256), 0, stream>>>(lU, Up);
  for (int ci = 0; ci < chunks; ++ci) {
    const int n0 = ci * NC;
    k_gemm<<<dim3(NC * 24 / 128, 2), dim3(512), 0, stream>>>(X, Wt, lb, XWc, n0);
    k_lstm<<<dim3(nseg), dim3(512), 0, stream>>>(XWc, Up, Atw, P, Sb,
                                                 n0, S, nseg,
                                                 ci == 0 ? 1 : 0, ci & 1);
  }
  k_ctx<<<dim3(256), dim3(320), 0, stream>>>(P, twW, twb, Atw, Btw, X, gW, gb, xg);
  k_gru<<<dim3(16), dim3(256), 0, stream>>>(gU, gb, xg, Hg);
  k_out<<<dim3(256), dim3(64), 0, stream>>>(Hg, linW, linb, out);
}

// Round 8
// 373.237 us; speedup vs baseline: 1.6146x; 1.0391x over previous
//
#include <hip/hip_runtime.h>
#include <hip/hip_bf16.h>
#include <cstdint>
#include <cstddef>
#include <initializer_list>

// Problem constants
#define WE    300
#define TEF   10
#define SLEN  24
#define HL    75      // H_LSTM
#define G4    300     // 4*HL
#define HG    77      // H_GRU
#define G3    231     // 3*HG
#define CLS   27
#define DIN   7210
#define NSTEP 4608
#define LBI   16      // LSTM segment burn-in (first emitted window gets >=28 warm steps at S=18)

typedef short    s16x8 __attribute__((ext_vector_type(8)));
typedef float    f32x4 __attribute__((ext_vector_type(4)));
typedef _Float16 f16x8 __attribute__((ext_vector_type(8)));
typedef _Float16 f16x4 __attribute__((ext_vector_type(4)));

static __device__ __forceinline__ unsigned short f2bf(float f) {
  unsigned u = __builtin_bit_cast(unsigned, f);
  unsigned r = u + 0x7fffu + ((u >> 16) & 1u);   // RNE
  return (unsigned short)(r >> 16);
}
static __device__ __forceinline__ unsigned packbf(float2 v) {
  return (unsigned)f2bf(v.x) | ((unsigned)f2bf(v.y) << 16);
}

static __device__ __forceinline__ float fast_exp2(float x) {
#if __has_builtin(__builtin_amdgcn_exp2f)
  return __builtin_amdgcn_exp2f(x);
#else
  return __exp2f(x);
#endif
}
static __device__ __forceinline__ float fast_rcp(float x) {
#if __has_builtin(__builtin_amdgcn_rcpf)
  return __builtin_amdgcn_rcpf(x);
#else
  return 1.0f / x;
#endif
}
static __device__ __forceinline__ float sigm(float x) {
  return fast_rcp(1.0f + fast_exp2(-1.4426950408889634f * x));
}
static __device__ __forceinline__ float tanh_f(float x) {
  return 2.0f * fast_rcp(1.0f + fast_exp2(-2.8853900817779268f * x)) - 1.0f;
}

// LDS-only barrier (global prefetch stays in flight)
static __device__ __forceinline__ void lds_barrier() {
  __asm__ volatile("s_waitcnt lgkmcnt(0)\n\ts_barrier" ::: "memory");
}

// ---------------------------------------------------------------------------
// Wt2 K-TILED: Wt2[kb][n][kk] = lstm_W[kb*32+kk][orig(n)], bf16, [10][320][32].
// Column permutation n = 4*e + gate (orig = gate*75+e).
// ---------------------------------------------------------------------------
__global__ __launch_bounds__(256) void k_prep_wt(const float* __restrict__ W,
                                                 unsigned short* __restrict__ Wt2) {
  int idx = blockIdx.x * 256 + threadIdx.x;
  if (idx >= 320 * 320) return;
  int n = idx / 320, k = idx - n * 320;
  float v = 0.0f;
  if (n < G4 && k < WE) {
    int e = n >> 2, g = n & 3;
    v = W[k * G4 + (g * 75 + e)];
  }
  size_t dst = ((size_t)(k >> 5) * 320 + n) * 32 + (k & 31);
  Wt2[dst] = f2bf(v);
}

// Upp[c][k] f16, [304][96]: Upp[c][k] = lstm_U[k][orig(c)], zero-padded.
__global__ __launch_bounds__(256) void k_prep_u(const float* __restrict__ U,
                                                unsigned short* __restrict__ Upp) {
  int idx = blockIdx.x * 256 + threadIdx.x;
  if (idx >= 304 * 96) return;
  int c = idx / 96, k = idx - c * 96;
  float v = 0.f;
  int e = c >> 2, g = c & 3;
  if (e < HL && k < HL) v = U[k * G4 + g * 75 + e];
  _Float16 hv = (_Float16)v;
  Upp[idx] = __builtin_bit_cast(unsigned short, hv);
}

// ---------------------------------------------------------------------------
// K1 v3: XWc(f16) = we @ lstm_W + lstm_b (permuted cols). Changes vs r7:
// (1) XWc stored as f16 (halves write bytes 133->66 MB and k_lstm's read);
//     values O(1..4) so f16 rounding ~5e-4, same order as existing h-f16.
// (2) LDS slot = row*5 + kgroup ("stride-5 chunks") for BOTH A and B:
//     staging writes AND b128 reads land at <=2-way bank aliasing (free),
//     fixing r7's self-inflicted 8.57M conflict cycles (~11% of dispatch).
// MFMA fragment DATA identical to r6/r7 (addresses only). grid (NC*24/128,2),
// 512 thr / 8 waves, acc[10] = 40 AGPR.
// ---------------------------------------------------------------------------
__global__ __launch_bounds__(512) void k_gemm(const float* __restrict__ X,
                                              const unsigned short* __restrict__ Wt2,
                                              const float* __restrict__ bvec,
                                              unsigned short* __restrict__ XWh, int n0) {
  __shared__ __align__(16) uint4 Ab[2][640];   // slot = rowA*5 + qtr   (20.5 KB)
  __shared__ __align__(16) uint4 Bb[2][800];   // slot = row*5 + sub    (25.6 KB)
  const int tid = threadIdx.x;
  const int wave = tid >> 6, lane = tid & 63;
  const int mlo = blockIdx.x * 128;
  const int nbase = blockIdx.y * 160;
  const int mrow = lane & 15, q4 = lane >> 4;

  // A staging: thread covers row rowA (0..127), bf16-cols [kb*32+qtr*8, +8)
  const int rowA = tid >> 2, qtr = tid & 3;
  const int mg = n0 * 24 + mlo + rowA;
  const int an = mg / 24, at = mg - an * 24;
  const float2* asrc2 = (const float2*)(X + (size_t)an * DIN + at * WE);  // 8B-aligned

  // B staging: 16B chunk o of the 640-chunk slab [kb][nbase..nbase+160][32]
  const int o0 = tid, o1 = tid + 512;
  const bool h1 = (tid < 128);
  const unsigned short* bsrc = Wt2 + (size_t)nbase * 32;   // + kb*10240 per kb

  f32x4 acc[10];
#pragma unroll
  for (int j = 0; j < 10; ++j) { acc[j][0] = 0.f; acc[j][1] = 0.f; acc[j][2] = 0.f; acc[j][3] = 0.f; }

  // prologue: stage kb=0 into buf 0
  {
    float2 af2[4];
#pragma unroll
    for (int p = 0; p < 4; ++p) af2[p] = asrc2[(qtr * 8 + 2 * p) >> 1];  // cols <= 30 < 300
    uint4 r0 = *(const uint4*)(bsrc + (size_t)o0 * 8);
    uint4 r1 = h1 ? *(const uint4*)(bsrc + (size_t)o1 * 8) : uint4{0, 0, 0, 0};
    uint4 w0;
    w0.x = packbf(af2[0]); w0.y = packbf(af2[1]); w0.z = packbf(af2[2]); w0.w = packbf(af2[3]);
    Ab[0][rowA * 5 + qtr] = w0;
    Bb[0][(o0 >> 2) * 5 + (o0 & 3)] = r0;
    if (h1) Bb[0][(o1 >> 2) * 5 + (o1 & 3)] = r1;
  }
  __syncthreads();

  for (int kb = 0; kb < 10; ++kb) {
    const int par = kb & 1;
    float2 af2[4];
    uint4 r0, r1;
    if (kb < 9) {
      const int base = (kb + 1) * 32 + qtr * 8;
#pragma unroll
      for (int p = 0; p < 4; ++p) {
        int cc = base + 2 * p;
        if (cc < WE) af2[p] = asrc2[cc >> 1];
        else { af2[p].x = 0.f; af2[p].y = 0.f; }
      }
      const unsigned short* bk = bsrc + (size_t)(kb + 1) * 10240;  // 320*32
      r0 = *(const uint4*)(bk + (size_t)o0 * 8);
      if (h1) r1 = *(const uint4*)(bk + (size_t)o1 * 8);
    }
    s16x8 fa = __builtin_bit_cast(s16x8, Ab[par][(wave * 16 + mrow) * 5 + q4]);
#pragma unroll
    for (int ni = 0; ni < 10; ++ni) {
      s16x8 fb = __builtin_bit_cast(s16x8, Bb[par][(ni * 16 + mrow) * 5 + q4]);
      acc[ni] = __builtin_amdgcn_mfma_f32_16x16x32_bf16(fa, fb, acc[ni], 0, 0, 0);
    }
    if (kb < 9) {
      uint4 w0;
      w0.x = packbf(af2[0]); w0.y = packbf(af2[1]); w0.z = packbf(af2[2]); w0.w = packbf(af2[3]);
      Ab[par ^ 1][rowA * 5 + qtr] = w0;
      Bb[par ^ 1][(o0 >> 2) * 5 + (o0 & 3)] = r0;
      if (h1) Bb[par ^ 1][(o1 >> 2) * 5 + (o1 & 3)] = r1;
    }
    __syncthreads();
  }

  // epilogue: C layout col=lane&15, row=(lane>>4)*4+reg; bias via orig(col); f16 store
#pragma unroll
  for (int ni = 0; ni < 10; ++ni) {
    int col = nbase + ni * 16 + mrow;
    if (col < G4) {
      int orig = (col & 3) * 75 + (col >> 2);
      float bv = bvec[orig];
#pragma unroll
      for (int reg = 0; reg < 4; ++reg) {
        int m = mlo + wave * 16 + q4 * 4 + reg;
        _Float16 hv = (_Float16)(acc[ni][reg] + bv);
        XWh[(size_t)m * G4 + col] = __builtin_bit_cast(unsigned short, hv);
      }
    }
  }
}

// ---------------------------------------------------------------------------
// K2: MFMA batched-chain LSTM (r6-verified structure). One 512-thread block
// per segment, all 24 chains per block. Z = U_perm(304x96 f16, regs) @
// H(32x96 f16, LDS dbuf) via mfma_f32_16x16x32_f16; activation lane-local
// via gate-interleaved columns. r8: XW read as f16x4 (+convert) — halves
// the dominant HBM read stream.
// ---------------------------------------------------------------------------
#define NTMAX 3

#define LSTM_STEP2(MM, BUF, XC)                                                        \
  {                                                                                    \
    const int mm = (MM);                                                               \
    f16x8 hf[2][3];                                                                    \
    _Pragma("unroll")                                                                  \
    for (int tt = 0; tt < 2; ++tt)                                                     \
      _Pragma("unroll")                                                                \
      for (int kg = 0; kg < 3; ++kg)                                                   \
        hf[tt][kg] = *(const f16x8*)&Hl[BUF][tt * 16 + lm][kg * 32 + lk * 8];          \
    f32x4 ac[NTMAX][2];                                                                \
    _Pragma("unroll")                                                                  \
    for (int i = 0; i < NTMAX; ++i) if (i < NT) {                                      \
      _Pragma("unroll")                                                                \
      for (int tt = 0; tt < 2; ++tt) {                                                 \
        f32x4 a = {0.f, 0.f, 0.f, 0.f};                                                \
        a = __builtin_amdgcn_mfma_f32_16x16x32_f16(u[i][0], hf[tt][0], a, 0, 0, 0);    \
        a = __builtin_amdgcn_mfma_f32_16x16x32_f16(u[i][1], hf[tt][1], a, 0, 0, 0);    \
        a = __builtin_amdgcn_mfma_f32_16x16x32_f16(u[i][2], hf[tt][2], a, 0, 0, 0);    \
        ac[i][tt] = a;                                                                 \
      }                                                                                \
    }                                                                                  \
    const int ng = gbase + mm;                                                         \
    const int bi = ng / 18;                                                            \
    const int rr = ng - bi * 18;                                                       \
    const bool win = (rr >= 12);                                                       \
    float aw = 0.f;                                                                    \
    if (win)                                                                           \
      aw = (rr == 12) ? aA[0] : (rr == 13) ? aA[1] : (rr == 14) ? aA[2]                \
         : (rr == 15) ? aA[3] : (rr == 16) ? aA[4] : aA[5];                            \
    const bool fl = (rr == 17) && (ng >= out_lo);                                      \
    const bool ldok = (mm + 2 < count);                                                \
    _Pragma("unroll")                                                                  \
    for (int i = 0; i < NTMAX; ++i) if (i < NT) {                                      \
      const int e = (w + 8 * i) * 4 + lk;                                              \
      _Pragma("unroll")                                                                \
      for (int tt = 0; tt < 2; ++tt) {                                                 \
        const int t = tt * 16 + lm;                                                    \
        const bool val = (t < 24) && (e < HL);                                         \
        f32x4 z4 = ac[i][tt] + __builtin_convertvector(XC[i][tt], f32x4);              \
        if (ldok && val)                                                               \
          XC[i][tt] = __builtin_bit_cast(f16x4,                                        \
            *(const uint2*)(Xh + ((size_t)(start + mm + 2) * 24 + t) * G4 + 4 * e));   \
        float si = sigm(z4[0]);                                                        \
        float sf = sigm(z4[1]);                                                        \
        float tg = tanh_f(z4[2]);                                                      \
        float so = sigm(z4[3]);                                                        \
        float c = fmaf(sf, cst[i][tt], si * tg);                                       \
        cst[i][tt] = c;                                                                \
        float h = so * tanh_f(c);                                                      \
        hlv[i][tt] = h;                                                                \
        if (val) {                                                                     \
          _Float16 hh = (_Float16)h;                                                   \
          Hl[(BUF) ^ 1][t][e] = __builtin_bit_cast(unsigned short, hh);                \
        }                                                                              \
        if (win) {                                                                     \
          accA[i][tt] = fmaf(aw, h, accA[i][tt]);                                      \
          if (fl) {                                                                    \
            if (val) P[((size_t)((t << 8) + bi)) * 76 + e] = accA[i][tt];              \
            accA[i][tt] = 0.f;                                                         \
          }                                                                            \
        }                                                                              \
      }                                                                                \
    }                                                                                  \
    lds_barrier();                                                                     \
  }

__global__ __launch_bounds__(512) void k_lstm(const unsigned short* __restrict__ Xh,
                                              const unsigned short* __restrict__ Upp,
                                              const float* __restrict__ Atw,
                                              float* __restrict__ P,
                                              float* __restrict__ Sbuf,
                                              int n0, int S, int nseg,
                                              int first, int parity) {
  __shared__ __align__(16) unsigned short Hl[2][32][104];  // 13.3 KB, dbuf
  const int tid = threadIdx.x;
  const int w = tid >> 6, l = tid & 63;
  const int lm = l & 15;          // t within 16-tile; B fragment row
  const int lk = l >> 4;          // 0..3: e_local; k-subgroup
  const int seg = blockIdx.x;
  const int NT = (w < 3) ? 3 : 2; // M-tiles {w, w+8, w+16(w<3)} cover 0..18

  const int start = seg * S - (seg ? LBI : 0);
  const int count = S + (seg ? LBI : 0);
  const int gbase = n0 + start;
  const int out_lo = n0 + seg * S;

  f16x8 u[NTMAX][3];
#pragma unroll
  for (int i = 0; i < NTMAX; ++i) if (i < NT) {
    const int col = (w + 8 * i) * 16 + lm;   // <= 303
#pragma unroll
    for (int kg = 0; kg < 3; ++kg)
      u[i][kg] = __builtin_bit_cast(f16x8, *(const uint4*)(Upp + (size_t)col * 96 + kg * 32 + lk * 8));
  }

  float aA[6];
#pragma unroll
  for (int k = 0; k < 6; ++k) aA[k] = Atw[k];

  {
    unsigned* hz = (unsigned*)&Hl[0][0][0];
    for (int i = tid; i < 2 * 32 * 104 / 2; i += 512) hz[i] = 0;
  }

  float cst[NTMAX][2], hlv[NTMAX][2], accA[NTMAX][2];
#pragma unroll
  for (int i = 0; i < NTMAX; ++i)
#pragma unroll
    for (int tt = 0; tt < 2; ++tt) { cst[i][tt] = 0.f; hlv[i][tt] = 0.f; accA[i][tt] = 0.f; }

  __syncthreads();  // Hl zero visible

  if (seg == 0 && !first) {
#pragma unroll
    for (int i = 0; i < NTMAX; ++i) if (i < NT) {
      const int e = (w + 8 * i) * 4 + lk;
#pragma unroll
      for (int tt = 0; tt < 2; ++tt) {
        const int t = tt * 16 + lm;
        if (t < 24 && e < HL) {
          const float* Sp = Sbuf + (size_t)(parity * 24 + t) * 160;
          cst[i][tt] = Sp[e];
          float hv = Sp[80 + e];
          hlv[i][tt] = hv;
          _Float16 hh = (_Float16)hv;
          Hl[0][t][e] = __builtin_bit_cast(unsigned short, hh);
        }
      }
    }
  }

  f16x4 XA[NTMAX][2], XB[NTMAX][2];
#pragma unroll
  for (int i = 0; i < NTMAX; ++i)
#pragma unroll
    for (int tt = 0; tt < 2; ++tt) {
      XA[i][tt] = __builtin_bit_cast(f16x4, uint2{0, 0});
      XB[i][tt] = __builtin_bit_cast(f16x4, uint2{0, 0});
    }
#pragma unroll
  for (int i = 0; i < NTMAX; ++i) if (i < NT) {
    const int e = (w + 8 * i) * 4 + lk;
#pragma unroll
    for (int tt = 0; tt < 2; ++tt) {
      const int t = tt * 16 + lm;
      if (t < 24 && e < HL) {
        XA[i][tt] = __builtin_bit_cast(f16x4, *(const uint2*)(Xh + ((size_t)(start + 0) * 24 + t) * G4 + 4 * e));
        XB[i][tt] = __builtin_bit_cast(f16x4, *(const uint2*)(Xh + ((size_t)(start + 1) * 24 + t) * G4 + 4 * e));
      }
    }
  }
  __syncthreads();  // initial h visible

  for (int m = 0; m < count; m += 2) {
    LSTM_STEP2(m,     0, XA)
    LSTM_STEP2(m + 1, 1, XB)
  }

  if (seg == nseg - 1) {
#pragma unroll
    for (int i = 0; i < NTMAX; ++i) if (i < NT) {
      const int e = (w + 8 * i) * 4 + lk;
#pragma unroll
      for (int tt = 0; tt < 2; ++tt) {
        const int t = tt * 16 + lm;
        if (t < 24 && e < HL) {
          float* Sp = Sbuf + (size_t)((parity ^ 1) * 24 + t) * 160;
          Sp[e] = cst[i][tt];
          Sp[80 + e] = hlv[i][tt];
        }
      }
    }
  }
}

// ---------------------------------------------------------------------------
// K3: hA -> ctx (ut==2) -> xg = ctx@gru_W + gru_b[0]. grid 256, 320 thr.
// ---------------------------------------------------------------------------
__global__ __launch_bounds__(320) void k_ctx(const float* __restrict__ P,
                                             const float* __restrict__ Wtw,
                                             const float* __restrict__ btw,
                                             const float* __restrict__ Atw,
                                             const float* __restrict__ Btw,
                                             const float* __restrict__ X,
                                             const float* __restrict__ Wg,
                                             const float* __restrict__ bg,
                                             float* __restrict__ xg) {
  __shared__ float hA[76];
  __shared__ float ctx[312];
  const int b = blockIdx.x, j = threadIdx.x;
  if (j < HL) {
    float s = 0.f;
    for (int t = 0; t < SLEN; ++t) s += P[((t << 8) + b) * 76 + j];
    hA[j] = s * (1.0f / 24.0f);
  }
  __syncthreads();
  if (j < G4) {
    float SA = Atw[0] + Atw[1] + Atw[2] + Atw[3] + Atw[4] + Atw[5];
    float s = SA * btw[j];
    for (int k = 0; k < HL; ++k) s = fmaf(hA[k], Wtw[k * G4 + j], s);
    ctx[j] = s * (1000.0f / 1001.0f) + Btw[0];
  } else if (j < 310) {
    int f = j - G4;
    float s = 0.f;
#pragma unroll
    for (int nt = 0; nt < 6; ++nt)
      s = fmaf(Atw[nt], X[(size_t)((b * 3 + 2) * 6 + nt) * DIN + 7200 + f], s);
    ctx[j] = s * (1.0f / 1001.0f) + Btw[0];
  }
  __syncthreads();
  if (j < G3) {
    float s = bg[j];
    for (int f = 0; f < 310; ++f) s = fmaf(ctx[f], Wg[f * G3 + j], s);
    xg[b * 240 + j] = s;
  }
}

// ---------------------------------------------------------------------------
// K5: segmented GRU (chain ut==2). grid 16 blocks x 256 thr.
// ---------------------------------------------------------------------------
#define GRU_STEP(B, PF)                                                                \
  {                                                                                    \
    if (q < G3) {                                                                      \
      const float4* h4 = (const float4*)gh;                                            \
      float a0 = b1, a1 = 0.f, a2 = 0.f, a3 = 0.f;                                     \
      _Pragma("unroll")                                                                \
      for (int p = 0; p < 20; ++p) {                                                   \
        float4 hv = h4[p];                                                             \
        a0 = fmaf(ug[4 * p + 0], hv.x, a0);                                            \
        a1 = fmaf(ug[4 * p + 1], hv.y, a1);                                            \
        a2 = fmaf(ug[4 * p + 2], hv.z, a2);                                            \
        a3 = fmaf(ug[4 * p + 3], hv.w, a3);                                            \
      }                                                                                \
      float rs = (a0 + a1) + (a2 + a3);                                                \
      float pnew = ((B) + 2 < 256) ? xg[((B) + 2) * 240 + q] : 0.f;                    \
      if (q < HG) {                                                                    \
        zreg = sigm((PF) + rs);                                                        \
      } else if (q < 154) {                                                            \
        rbuf[q - 77] = sigm((PF) + rs);                                                \
      } else {                                                                         \
        xkeep = (PF);                                                                  \
        rkeep = rs;                                                                    \
      }                                                                                \
      (PF) = pnew;                                                                     \
    }                                                                                  \
    lds_barrier();                                                                     \
    if (q >= 154 && q < G3) hhb[q - 154] = tanh_f(xkeep + rbuf[q - 154] * rkeep);      \
    lds_barrier();                                                                     \
    if (q < HG) {                                                                      \
      float hh = hhb[q];                                                               \
      hq = zreg * hq + (1.0f - zreg) * hh;                                             \
      gh[q] = hq;                                                                      \
      if ((B) >= out_lo) Hg[(B) * 80 + q] = hq;                                        \
    }                                                                                  \
    lds_barrier();                                                                     \
  }

__global__ __launch_bounds__(256) void k_gru(const float* __restrict__ Ug,
                                             const float* __restrict__ bg,
                                             const float* __restrict__ xg,
                                             float* __restrict__ Hg) {
  __shared__ __align__(16) float gh[80];
  __shared__ float rbuf[77];
  __shared__ float hhb[77];
  const int q = threadIdx.x;
  const int b0 = blockIdx.x;
  const int out_lo = b0 * 16;
  const int start = b0 ? (out_lo - 16) : 0;
  const int end = out_lo + 16;
  float ug[80];
  float b1 = 0.f;
  if (q < G3) {
    b1 = bg[G3 + q];
#pragma unroll
    for (int k = 0; k < 80; ++k) ug[k] = (k < HG) ? Ug[k * G3 + q] : 0.f;
  }
  if (q < 80) gh[q] = 0.f;
  float hq = 0.f, zreg = 0.f, xkeep = 0.f, rkeep = 0.f;
  float pf0 = (q < G3) ? xg[start * 240 + q] : 0.f;
  float pf1 = (q < G3) ? xg[(start + 1) * 240 + q] : 0.f;
  __syncthreads();
  for (int b = start; b < end; b += 2) {
    GRU_STEP(b, pf0)
    GRU_STEP(b + 1, pf1)
  }
}

// ---------------------------------------------------------------------------
__global__ __launch_bounds__(64) void k_out(const float* __restrict__ Hg,
                                            const float* __restrict__ Wl,
                                            const float* __restrict__ bl,
                                            float* __restrict__ out) {
  __shared__ float lb[CLS];
  __shared__ float eb[CLS];
  const int b = blockIdx.x, j = threadIdx.x;
  float lg = 0.f;
  if (j < CLS) {
    lg = bl[j];
    for (int k = 0; k < HG; ++k) lg = fmaf(Hg[b * 80 + k], Wl[k * CLS + j], lg);
    lb[j] = lg;
  }
  __syncthreads();
  float ex = 0.f;
  if (j < CLS) {
    float m = lb[0];
    for (int i = 1; i < CLS; ++i) m = fmaxf(m, lb[i]);
    ex = fast_exp2((lg - m) * 1.4426950408889634f);
    eb[j] = ex;
  }
  __syncthreads();
  if (j < CLS) {
    float s = 0.f;
    for (int i = 0; i < CLS; ++i) s += eb[i];
    out[b * CLS + j] = ex / s;
  }
}

// ---------------------------------------------------------------------------
extern "C" void kernel_launch(void* const* d_in, const int* in_sizes, int n_in,
                              void* d_out, int out_size, void* d_ws, size_t ws_size,
                              hipStream_t stream) {
  const float* X    = (const float*)d_in[0];
  const float* lW   = (const float*)d_in[1];
  const float* lU   = (const float*)d_in[2];
  const float* lb   = (const float*)d_in[3];
  const float* twW  = (const float*)d_in[4];
  const float* twb  = (const float*)d_in[5];
  const float* Atw  = (const float*)d_in[6];
  const float* Btw  = (const float*)d_in[7];
  const float* gW   = (const float*)d_in[8];
  const float* gU   = (const float*)d_in[9];
  const float* gb   = (const float*)d_in[10];
  const float* linW = (const float*)d_in[11];
  const float* linb = (const float*)d_in[12];
  float* out = (float*)d_out;

  char* ws = (char*)d_ws;
  unsigned short* Wt = (unsigned short*)(ws + 0);        // 204800 (k-tiled [10][320][32])
  unsigned short* Up = (unsigned short*)(ws + 204800);   // 58368 (304x96 f16)
  float* P   = (float*)(ws + 263168);                    // 1867776
  float* Sb  = (float*)(ws + 2130944);                   // 30720
  float* xg  = (float*)(ws + 2161664);                   // 245760
  float* Hg  = (float*)(ws + 2407424);                   // 81920
  unsigned short* XWc = (unsigned short*)(ws + 2489344); // NC*24*300*2 (full: 66.4 MB, f16)

  const size_t fixed = 2489344;
  int NC = 144;
  for (int k : {32, 16, 8, 4, 2, 1}) {
    size_t need = fixed + (size_t)144 * k * 14400;
    if (need <= ws_size) { NC = 144 * k; break; }
  }
  const int chunks = NSTEP / NC;
  // S=18: one 18-window per segment, nseg = NC/18 <= 256 (all CUs), 34
  // serial steps (16 burn-in + 18).
  int S = NC, nseg = 1;
  for (int s : {18, 24, 48, 96, 192, 288, 576}) {
    if (NC % s == 0 && NC / s <= 256) { S = s; nseg = NC / s; break; }
  }

  k_prep_wt<<<dim3(400), dim3(256), 0, stream>>>(lW, Wt);
  k_prep_u<<<dim3(114), dim3(256), 0, stream>>>(lU, Up);
  for (int ci = 0; ci < chunks; ++ci) {
    const int n0 = ci * NC;
    k_gemm<<<dim3(NC * 24 / 128, 2), dim3(512), 0, stream>>>(X, Wt, lb, XWc, n0);
    k_lstm<<<dim3(nseg), dim3(512), 0, stream>>>(XWc, Up, Atw, P, Sb,
                                                 n0, S, nseg,
                                                 ci == 0 ? 1 : 0, ci & 1);
  }
  k_ctx<<<dim3(256), dim3(320), 0, stream>>>(P, twW, twb, Atw, Btw, X, gW, gb, xg);
  k_gru<<<dim3(16), dim3(256), 0, stream>>>(gU, gb, xg, Hg);
  k_out<<<dim3(256), dim3(64), 0, stream>>>(Hg, linW, linb, out);
}

// Round 9
// 369.545 us; speedup vs baseline: 1.6307x; 1.0100x over previous
//
#include <hip/hip_runtime.h>
#include <hip/hip_bf16.h>
#include <cstdint>
#include <cstddef>
#include <initializer_list>

// Problem constants
#define WE    300
#define TEF   10
#define SLEN  24
#define HL    75      // H_LSTM
#define G4    300     // 4*HL
#define HG    77      // H_GRU
#define G3    231     // 3*HG
#define CLS   27
#define DIN   7210
#define NSTEP 4608
#define LBI   16      // LSTM segment burn-in (first emitted window gets >=28 warm steps at S=18)

typedef short    s16x8 __attribute__((ext_vector_type(8)));
typedef float    f32x4 __attribute__((ext_vector_type(4)));
typedef _Float16 f16x8 __attribute__((ext_vector_type(8)));
typedef _Float16 f16x4 __attribute__((ext_vector_type(4)));

static __device__ __forceinline__ unsigned short f2bf(float f) {
  unsigned u = __builtin_bit_cast(unsigned, f);
  unsigned r = u + 0x7fffu + ((u >> 16) & 1u);   // RNE
  return (unsigned short)(r >> 16);
}
static __device__ __forceinline__ unsigned packbf(float2 v) {
  return (unsigned)f2bf(v.x) | ((unsigned)f2bf(v.y) << 16);
}

static __device__ __forceinline__ float fast_exp2(float x) {
#if __has_builtin(__builtin_amdgcn_exp2f)
  return __builtin_amdgcn_exp2f(x);
#else
  return __exp2f(x);
#endif
}
static __device__ __forceinline__ float fast_rcp(float x) {
#if __has_builtin(__builtin_amdgcn_rcpf)
  return __builtin_amdgcn_rcpf(x);
#else
  return 1.0f / x;
#endif
}
static __device__ __forceinline__ float sigm(float x) {
  return fast_rcp(1.0f + fast_exp2(-1.4426950408889634f * x));
}
static __device__ __forceinline__ float tanh_f(float x) {
  return 2.0f * fast_rcp(1.0f + fast_exp2(-2.8853900817779268f * x)) - 1.0f;
}

// LDS-only barrier (global prefetch stays in flight)
static __device__ __forceinline__ void lds_barrier() {
  __asm__ volatile("s_waitcnt lgkmcnt(0)\n\ts_barrier" ::: "memory");
}

// ---------------------------------------------------------------------------
// Wt2 K-TILED: Wt2[kb][n][kk] = lstm_W[kb*32+kk][orig(n)], bf16, [10][320][32].
// Column permutation n = 4*e + gate (orig = gate*75+e).
// ---------------------------------------------------------------------------
__global__ __launch_bounds__(256) void k_prep_wt(const float* __restrict__ W,
                                                 unsigned short* __restrict__ Wt2) {
  int idx = blockIdx.x * 256 + threadIdx.x;
  if (idx >= 320 * 320) return;
  int n = idx / 320, k = idx - n * 320;
  float v = 0.0f;
  if (n < G4 && k < WE) {
    int e = n >> 2, g = n & 3;
    v = W[k * G4 + (g * 75 + e)];
  }
  size_t dst = ((size_t)(k >> 5) * 320 + n) * 32 + (k & 31);
  Wt2[dst] = f2bf(v);
}

// Upp[c][k] f16, [304][96]: Upp[c][k] = lstm_U[k][orig(c)], zero-padded.
__global__ __launch_bounds__(256) void k_prep_u(const float* __restrict__ U,
                                                unsigned short* __restrict__ Upp) {
  int idx = blockIdx.x * 256 + threadIdx.x;
  if (idx >= 304 * 96) return;
  int c = idx / 96, k = idx - c * 96;
  float v = 0.f;
  int e = c >> 2, g = c & 3;
  if (e < HL && k < HL) v = U[k * G4 + g * 75 + e];
  _Float16 hv = (_Float16)v;
  Upp[idx] = __builtin_bit_cast(unsigned short, hv);
}

// ---------------------------------------------------------------------------
// K1 v3 (r9: + mb0 split param): XWc(f16) = we @ lstm_W + lstm_b.
// Launched as TWO half-grid dispatches (mb0 = 0, NB/2) so k_lstm becomes
// visible in the top-5 profile. Everything else identical to r8 (verified).
// Note: SQ_LDS_BANK_CONFLICT ~8.57M is benign 2-way read aliasing (free per
// m136) — identical across two different layouts, not a time cost.
// ---------------------------------------------------------------------------
__global__ __launch_bounds__(512) void k_gemm(const float* __restrict__ X,
                                              const unsigned short* __restrict__ Wt2,
                                              const float* __restrict__ bvec,
                                              unsigned short* __restrict__ XWh,
                                              int n0, int mb0) {
  __shared__ __align__(16) uint4 Ab[2][640];   // slot = rowA*5 + qtr   (20.5 KB)
  __shared__ __align__(16) uint4 Bb[2][800];   // slot = row*5 + sub    (25.6 KB)
  const int tid = threadIdx.x;
  const int wave = tid >> 6, lane = tid & 63;
  const int mlo = (mb0 + blockIdx.x) * 128;
  const int nbase = blockIdx.y * 160;
  const int mrow = lane & 15, q4 = lane >> 4;

  // A staging: thread covers row rowA (0..127), bf16-cols [kb*32+qtr*8, +8)
  const int rowA = tid >> 2, qtr = tid & 3;
  const int mg = n0 * 24 + mlo + rowA;
  const int an = mg / 24, at = mg - an * 24;
  const float2* asrc2 = (const float2*)(X + (size_t)an * DIN + at * WE);  // 8B-aligned

  // B staging: 16B chunk o of the 640-chunk slab [kb][nbase..nbase+160][32]
  const int o0 = tid, o1 = tid + 512;
  const bool h1 = (tid < 128);
  const unsigned short* bsrc = Wt2 + (size_t)nbase * 32;   // + kb*10240 per kb

  f32x4 acc[10];
#pragma unroll
  for (int j = 0; j < 10; ++j) { acc[j][0] = 0.f; acc[j][1] = 0.f; acc[j][2] = 0.f; acc[j][3] = 0.f; }

  // prologue: stage kb=0 into buf 0
  {
    float2 af2[4];
#pragma unroll
    for (int p = 0; p < 4; ++p) af2[p] = asrc2[(qtr * 8 + 2 * p) >> 1];  // cols <= 30 < 300
    uint4 r0 = *(const uint4*)(bsrc + (size_t)o0 * 8);
    uint4 r1 = h1 ? *(const uint4*)(bsrc + (size_t)o1 * 8) : uint4{0, 0, 0, 0};
    uint4 w0;
    w0.x = packbf(af2[0]); w0.y = packbf(af2[1]); w0.z = packbf(af2[2]); w0.w = packbf(af2[3]);
    Ab[0][rowA * 5 + qtr] = w0;
    Bb[0][(o0 >> 2) * 5 + (o0 & 3)] = r0;
    if (h1) Bb[0][(o1 >> 2) * 5 + (o1 & 3)] = r1;
  }
  __syncthreads();

  for (int kb = 0; kb < 10; ++kb) {
    const int par = kb & 1;
    float2 af2[4];
    uint4 r0, r1;
    if (kb < 9) {
      const int base = (kb + 1) * 32 + qtr * 8;
#pragma unroll
      for (int p = 0; p < 4; ++p) {
        int cc = base + 2 * p;
        if (cc < WE) af2[p] = asrc2[cc >> 1];
        else { af2[p].x = 0.f; af2[p].y = 0.f; }
      }
      const unsigned short* bk = bsrc + (size_t)(kb + 1) * 10240;  // 320*32
      r0 = *(const uint4*)(bk + (size_t)o0 * 8);
      if (h1) r1 = *(const uint4*)(bk + (size_t)o1 * 8);
    }
    s16x8 fa = __builtin_bit_cast(s16x8, Ab[par][(wave * 16 + mrow) * 5 + q4]);
#pragma unroll
    for (int ni = 0; ni < 10; ++ni) {
      s16x8 fb = __builtin_bit_cast(s16x8, Bb[par][(ni * 16 + mrow) * 5 + q4]);
      acc[ni] = __builtin_amdgcn_mfma_f32_16x16x32_bf16(fa, fb, acc[ni], 0, 0, 0);
    }
    if (kb < 9) {
      uint4 w0;
      w0.x = packbf(af2[0]); w0.y = packbf(af2[1]); w0.z = packbf(af2[2]); w0.w = packbf(af2[3]);
      Ab[par ^ 1][rowA * 5 + qtr] = w0;
      Bb[par ^ 1][(o0 >> 2) * 5 + (o0 & 3)] = r0;
      if (h1) Bb[par ^ 1][(o1 >> 2) * 5 + (o1 & 3)] = r1;
    }
    __syncthreads();
  }

  // epilogue: C layout col=lane&15, row=(lane>>4)*4+reg; bias via orig(col); f16 store
#pragma unroll
  for (int ni = 0; ni < 10; ++ni) {
    int col = nbase + ni * 16 + mrow;
    if (col < G4) {
      int orig = (col & 3) * 75 + (col >> 2);
      float bv = bvec[orig];
#pragma unroll
      for (int reg = 0; reg < 4; ++reg) {
        int m = mlo + wave * 16 + q4 * 4 + reg;
        _Float16 hv = (_Float16)(acc[ni][reg] + bv);
        XWh[(size_t)m * G4 + col] = __builtin_bit_cast(unsigned short, hv);
      }
    }
  }
}

// ---------------------------------------------------------------------------
// K2 r9: t-SPLIT MFMA batched-chain LSTM. The 24 chains per segment are
// independent -> split across 2 blocks (t 0-11 / 12-23), grid 2*nseg=512,
// 2 blocks/CU. Rationale: r7->r8 showed k_lstm is NOT HBM-bound (halving
// its read stream moved "rest" only 267->263us); at 1 block/CU it is a
// single barrier-locked dependence chain (~6000 cyc/step vs ~1-2K static
// work) -> latency-bound. Two independent chains per CU overlap each
// other's stalls. MFMA padding efficiency unchanged (16-cols-for-12 twice
// vs 2x16-for-24: both 75%). Per-chain arithmetic identical -> absmax
// bit-identical. Per block: Z = U_perm(304x96 f16, regs) @ H(16x96 f16,
// LDS dbuf) via mfma_f32_16x16x32_f16; activation lane-local.
// ---------------------------------------------------------------------------
#define NTMAX 3

#define LSTM_STEP2(MM, BUF, XC)                                                        \
  {                                                                                    \
    const int mm = (MM);                                                               \
    f16x8 hf[3];                                                                       \
    _Pragma("unroll")                                                                  \
    for (int kg = 0; kg < 3; ++kg)                                                     \
      hf[kg] = *(const f16x8*)&Hl[BUF][lm][kg * 32 + lk * 8];                          \
    f32x4 ac[NTMAX];                                                                   \
    _Pragma("unroll")                                                                  \
    for (int i = 0; i < NTMAX; ++i) if (i < NT) {                                      \
      f32x4 a = {0.f, 0.f, 0.f, 0.f};                                                  \
      a = __builtin_amdgcn_mfma_f32_16x16x32_f16(u[i][0], hf[0], a, 0, 0, 0);          \
      a = __builtin_amdgcn_mfma_f32_16x16x32_f16(u[i][1], hf[1], a, 0, 0, 0);          \
      a = __builtin_amdgcn_mfma_f32_16x16x32_f16(u[i][2], hf[2], a, 0, 0, 0);          \
      ac[i] = a;                                                                       \
    }                                                                                  \
    const int ng = gbase + mm;                                                         \
    const int bi = ng / 18;                                                            \
    const int rr = ng - bi * 18;                                                       \
    const bool win = (rr >= 12);                                                       \
    float aw = 0.f;                                                                    \
    if (win)                                                                           \
      aw = (rr == 12) ? aA[0] : (rr == 13) ? aA[1] : (rr == 14) ? aA[2]                \
         : (rr == 15) ? aA[3] : (rr == 16) ? aA[4] : aA[5];                            \
    const bool fl = (rr == 17) && (ng >= out_lo);                                      \
    const bool ldok = (mm + 2 < count);                                                \
    _Pragma("unroll")                                                                  \
    for (int i = 0; i < NTMAX; ++i) if (i < NT) {                                      \
      const int e = (w + 8 * i) * 4 + lk;                                              \
      const bool val = (lm < 12) && (e < HL);                                          \
      f32x4 z4 = ac[i] + __builtin_convertvector(XC[i], f32x4);                        \
      if (ldok && val)                                                                 \
        XC[i] = __builtin_bit_cast(f16x4,                                              \
          *(const uint2*)(Xh + ((size_t)(start + mm + 2) * 24 + tg) * G4 + 4 * e));    \
      float si = sigm(z4[0]);                                                          \
      float sf = sigm(z4[1]);                                                          \
      float tgv = tanh_f(z4[2]);                                                       \
      float so = sigm(z4[3]);                                                          \
      float c = fmaf(sf, cst[i], si * tgv);                                            \
      cst[i] = c;                                                                      \
      float h = so * tanh_f(c);                                                        \
      hlv[i] = h;                                                                      \
      if (val) {                                                                       \
        _Float16 hh = (_Float16)h;                                                     \
        Hl[(BUF) ^ 1][lm][e] = __builtin_bit_cast(unsigned short, hh);                 \
      }                                                                                \
      if (win) {                                                                       \
        accA[i] = fmaf(aw, h, accA[i]);                                                \
        if (fl) {                                                                      \
          if (val) P[((size_t)((tg << 8) + bi)) * 76 + e] = accA[i];                   \
          accA[i] = 0.f;                                                               \
        }                                                                              \
      }                                                                                \
    }                                                                                  \
    lds_barrier();                                                                     \
  }

__global__ __launch_bounds__(512) void k_lstm(const unsigned short* __restrict__ Xh,
                                              const unsigned short* __restrict__ Upp,
                                              const float* __restrict__ Atw,
                                              float* __restrict__ P,
                                              float* __restrict__ Sbuf,
                                              int n0, int S, int nseg,
                                              int first, int parity) {
  __shared__ __align__(16) unsigned short Hl[2][16][104];  // 6.7 KB, dbuf
  const int tid = threadIdx.x;
  const int w = tid >> 6, l = tid & 63;
  const int lm = l & 15;          // local t (chain) / B fragment col
  const int lk = l >> 4;          // 0..3: e_local; k-subgroup
  const int seg = blockIdx.x >> 1;
  const int t0 = (blockIdx.x & 1) * 12;
  const int tg = t0 + lm;         // global chain id (valid when lm < 12)
  const int NT = (w < 3) ? 3 : 2; // M-tiles {w, w+8, w+16(w<3)} cover 0..18

  const int start = seg * S - (seg ? LBI : 0);
  const int count = S + (seg ? LBI : 0);
  const int gbase = n0 + start;
  const int out_lo = n0 + seg * S;

  f16x8 u[NTMAX][3];
#pragma unroll
  for (int i = 0; i < NTMAX; ++i) if (i < NT) {
    const int col = (w + 8 * i) * 16 + lm;   // <= 303
#pragma unroll
    for (int kg = 0; kg < 3; ++kg)
      u[i][kg] = __builtin_bit_cast(f16x8, *(const uint4*)(Upp + (size_t)col * 96 + kg * 32 + lk * 8));
  }

  float aA[6];
#pragma unroll
  for (int k = 0; k < 6; ++k) aA[k] = Atw[k];

  {
    unsigned* hz = (unsigned*)&Hl[0][0][0];
    for (int i = tid; i < 2 * 16 * 104 / 2; i += 512) hz[i] = 0;
  }

  float cst[NTMAX], hlv[NTMAX], accA[NTMAX];
#pragma unroll
  for (int i = 0; i < NTMAX; ++i) { cst[i] = 0.f; hlv[i] = 0.f; accA[i] = 0.f; }

  __syncthreads();  // Hl zero visible

  if (seg == 0 && !first) {
#pragma unroll
    for (int i = 0; i < NTMAX; ++i) if (i < NT) {
      const int e = (w + 8 * i) * 4 + lk;
      if (lm < 12 && e < HL) {
        const float* Sp = Sbuf + (size_t)(parity * 24 + tg) * 160;
        cst[i] = Sp[e];
        float hv = Sp[80 + e];
        hlv[i] = hv;
        _Float16 hh = (_Float16)hv;
        Hl[0][lm][e] = __builtin_bit_cast(unsigned short, hh);
      }
    }
  }

  f16x4 XA[NTMAX], XB[NTMAX];
#pragma unroll
  for (int i = 0; i < NTMAX; ++i) {
    XA[i] = __builtin_bit_cast(f16x4, uint2{0, 0});
    XB[i] = __builtin_bit_cast(f16x4, uint2{0, 0});
  }
#pragma unroll
  for (int i = 0; i < NTMAX; ++i) if (i < NT) {
    const int e = (w + 8 * i) * 4 + lk;
    if (lm < 12 && e < HL) {
      XA[i] = __builtin_bit_cast(f16x4, *(const uint2*)(Xh + ((size_t)(start + 0) * 24 + tg) * G4 + 4 * e));
      XB[i] = __builtin_bit_cast(f16x4, *(const uint2*)(Xh + ((size_t)(start + 1) * 24 + tg) * G4 + 4 * e));
    }
  }
  __syncthreads();  // initial h visible

  for (int m = 0; m < count; m += 2) {
    LSTM_STEP2(m,     0, XA)
    LSTM_STEP2(m + 1, 1, XB)
  }

  if (seg == nseg - 1) {
#pragma unroll
    for (int i = 0; i < NTMAX; ++i) if (i < NT) {
      const int e = (w + 8 * i) * 4 + lk;
      if (lm < 12 && e < HL) {
        float* Sp = Sbuf + (size_t)((parity ^ 1) * 24 + tg) * 160;
        Sp[e] = cst[i];
        Sp[80 + e] = hlv[i];
      }
    }
  }
}

// ---------------------------------------------------------------------------
// K3: hA -> ctx (ut==2) -> xg = ctx@gru_W + gru_b[0]. grid 256, 320 thr.
// ---------------------------------------------------------------------------
__global__ __launch_bounds__(320) void k_ctx(const float* __restrict__ P,
                                             const float* __restrict__ Wtw,
                                             const float* __restrict__ btw,
                                             const float* __restrict__ Atw,
                                             const float* __restrict__ Btw,
                                             const float* __restrict__ X,
                                             const float* __restrict__ Wg,
                                             const float* __restrict__ bg,
                                             float* __restrict__ xg) {
  __shared__ float hA[76];
  __shared__ float ctx[312];
  const int b = blockIdx.x, j = threadIdx.x;
  if (j < HL) {
    float s = 0.f;
    for (int t = 0; t < SLEN; ++t) s += P[((t << 8) + b) * 76 + j];
    hA[j] = s * (1.0f / 24.0f);
  }
  __syncthreads();
  if (j < G4) {
    float SA = Atw[0] + Atw[1] + Atw[2] + Atw[3] + Atw[4] + Atw[5];
    float s = SA * btw[j];
    for (int k = 0; k < HL; ++k) s = fmaf(hA[k], Wtw[k * G4 + j], s);
    ctx[j] = s * (1000.0f / 1001.0f) + Btw[0];
  } else if (j < 310) {
    int f = j - G4;
    float s = 0.f;
#pragma unroll
    for (int nt = 0; nt < 6; ++nt)
      s = fmaf(Atw[nt], X[(size_t)((b * 3 + 2) * 6 + nt) * DIN + 7200 + f], s);
    ctx[j] = s * (1.0f / 1001.0f) + Btw[0];
  }
  __syncthreads();
  if (j < G3) {
    float s = bg[j];
    for (int f = 0; f < 310; ++f) s = fmaf(ctx[f], Wg[f * G3 + j], s);
    xg[b * 240 + j] = s;
  }
}

// ---------------------------------------------------------------------------
// K5: segmented GRU (chain ut==2). grid 16 blocks x 256 thr.
// ---------------------------------------------------------------------------
#define GRU_STEP(B, PF)                                                                \
  {                                                                                    \
    if (q < G3) {                                                                      \
      const float4* h4 = (const float4*)gh;                                            \
      float a0 = b1, a1 = 0.f, a2 = 0.f, a3 = 0.f;                                     \
      _Pragma("unroll")                                                                \
      for (int p = 0; p < 20; ++p) {                                                   \
        float4 hv = h4[p];                                                             \
        a0 = fmaf(ug[4 * p + 0], hv.x, a0);                                            \
        a1 = fmaf(ug[4 * p + 1], hv.y, a1);                                            \
        a2 = fmaf(ug[4 * p + 2], hv.z, a2);                                            \
        a3 = fmaf(ug[4 * p + 3], hv.w, a3);                                            \
      }                                                                                \
      float rs = (a0 + a1) + (a2 + a3);                                                \
      float pnew = ((B) + 2 < 256) ? xg[((B) + 2) * 240 + q] : 0.f;                    \
      if (q < HG) {                                                                    \
        zreg = sigm((PF) + rs);                                                        \
      } else if (q < 154) {                                                            \
        rbuf[q - 77] = sigm((PF) + rs);                                                \
      } else {                                                                         \
        xkeep = (PF);                                                                  \
        rkeep = rs;                                                                    \
      }                                                                                \
      (PF) = pnew;                                                                     \
    }                                                                                  \
    lds_barrier();                                                                     \
    if (q >= 154 && q < G3) hhb[q - 154] = tanh_f(xkeep + rbuf[q - 154] * rkeep);      \
    lds_barrier();                                                                     \
    if (q < HG) {                                                                      \
      float hh = hhb[q];                                                               \
      hq = zreg * hq + (1.0f - zreg) * hh;                                             \
      gh[q] = hq;                                                                      \
      if ((B) >= out_lo) Hg[(B) * 80 + q] = hq;                                        \
    }                                                                                  \
    lds_barrier();                                                                     \
  }

__global__ __launch_bounds__(256) void k_gru(const float* __restrict__ Ug,
                                             const float* __restrict__ bg,
                                             const float* __restrict__ xg,
                                             float* __restrict__ Hg) {
  __shared__ __align__(16) float gh[80];
  __shared__ float rbuf[77];
  __shared__ float hhb[77];
  const int q = threadIdx.x;
  const int b0 = blockIdx.x;
  const int out_lo = b0 * 16;
  const int start = b0 ? (out_lo - 16) : 0;
  const int end = out_lo + 16;
  float ug[80];
  float b1 = 0.f;
  if (q < G3) {
    b1 = bg[G3 + q];
#pragma unroll
    for (int k = 0; k < 80; ++k) ug[k] = (k < HG) ? Ug[k * G3 + q] : 0.f;
  }
  if (q < 80) gh[q] = 0.f;
  float hq = 0.f, zreg = 0.f, xkeep = 0.f, rkeep = 0.f;
  float pf0 = (q < G3) ? xg[start * 240 + q] : 0.f;
  float pf1 = (q < G3) ? xg[(start + 1) * 240 + q] : 0.f;
  __syncthreads();
  for (int b = start; b < end; b += 2) {
    GRU_STEP(b, pf0)
    GRU_STEP(b + 1, pf1)
  }
}

// ---------------------------------------------------------------------------
__global__ __launch_bounds__(64) void k_out(const float* __restrict__ Hg,
                                            const float* __restrict__ Wl,
                                            const float* __restrict__ bl,
                                            float* __restrict__ out) {
  __shared__ float lb[CLS];
  __shared__ float eb[CLS];
  const int b = blockIdx.x, j = threadIdx.x;
  float lg = 0.f;
  if (j < CLS) {
    lg = bl[j];
    for (int k = 0; k < HG; ++k) lg = fmaf(Hg[b * 80 + k], Wl[k * CLS + j], lg);
    lb[j] = lg;
  }
  __syncthreads();
  float ex = 0.f;
  if (j < CLS) {
    float m = lb[0];
    for (int i = 1; i < CLS; ++i) m = fmaxf(m, lb[i]);
    ex = fast_exp2((lg - m) * 1.4426950408889634f);
    eb[j] = ex;
  }
  __syncthreads();
  if (j < CLS) {
    float s = 0.f;
    for (int i = 0; i < CLS; ++i) s += eb[i];
    out[b * CLS + j] = ex / s;
  }
}

// ---------------------------------------------------------------------------
extern "C" void kernel_launch(void* const* d_in, const int* in_sizes, int n_in,
                              void* d_out, int out_size, void* d_ws, size_t ws_size,
                              hipStream_t stream) {
  const float* X    = (const float*)d_in[0];
  const float* lW   = (const float*)d_in[1];
  const float* lU   = (const float*)d_in[2];
  const float* lb   = (const float*)d_in[3];
  const float* twW  = (const float*)d_in[4];
  const float* twb  = (const float*)d_in[5];
  const float* Atw  = (const float*)d_in[6];
  const float* Btw  = (const float*)d_in[7];
  const float* gW   = (const float*)d_in[8];
  const float* gU   = (const float*)d_in[9];
  const float* gb   = (const float*)d_in[10];
  const float* linW = (const float*)d_in[11];
  const float* linb = (const float*)d_in[12];
  float* out = (float*)d_out;

  char* ws = (char*)d_ws;
  unsigned short* Wt = (unsigned short*)(ws + 0);        // 204800 (k-tiled [10][320][32])
  unsigned short* Up = (unsigned short*)(ws + 204800);   // 58368 (304x96 f16)
  float* P   = (float*)(ws + 263168);                    // 1867776
  float* Sb  = (float*)(ws + 2130944);                   // 30720
  float* xg  = (float*)(ws + 2161664);                   // 245760
  float* Hg  = (float*)(ws + 2407424);                   // 81920
  unsigned short* XWc = (unsigned short*)(ws + 2489344); // NC*24*300*2 (full: 66.4 MB, f16)

  const size_t fixed = 2489344;
  int NC = 144;
  for (int k : {32, 16, 8, 4, 2, 1}) {
    size_t need = fixed + (size_t)144 * k * 14400;
    if (need <= ws_size) { NC = 144 * k; break; }
  }
  const int chunks = NSTEP / NC;
  // S=18: one 18-window per segment; nseg = NC/18 <= 256; k_lstm grid is
  // 2*nseg (t-split) -> 512 blocks = 2/CU.
  int S = NC, nseg = 1;
  for (int s : {18, 24, 48, 96, 192, 288, 576}) {
    if (NC % s == 0 && NC / s <= 256) { S = s; nseg = NC / s; break; }
  }

  k_prep_wt<<<dim3(400), dim3(256), 0, stream>>>(lW, Wt);
  k_prep_u<<<dim3(114), dim3(256), 0, stream>>>(lU, Up);
  for (int ci = 0; ci < chunks; ++ci) {
    const int n0 = ci * NC;
    const int NB = NC * 24 / 128;
    k_gemm<<<dim3(NB / 2, 2), dim3(512), 0, stream>>>(X, Wt, lb, XWc, n0, 0);
    k_gemm<<<dim3(NB / 2, 2), dim3(512), 0, stream>>>(X, Wt, lb, XWc, n0, NB / 2);
    k_lstm<<<dim3(nseg * 2), dim3(512), 0, stream>>>(XWc, Up, Atw, P, Sb,
                                                     n0, S, nseg,
                                                     ci == 0 ? 1 : 0, ci & 1);
  }
  k_ctx<<<dim3(256), dim3(320), 0, stream>>>(P, twW, twb, Atw, Btw, X, gW, gb, xg);
  k_gru<<<dim3(16), dim3(256), 0, stream>>>(gU, gb, xg, Hg);
  k_out<<<dim3(256), dim3(64), 0, stream>>>(Hg, linW, linb, out);
}

// Round 10
// 364.279 us; speedup vs baseline: 1.6543x; 1.0145x over previous
//
#include <hip/hip_runtime.h>
#include <hip/hip_bf16.h>
#include <cstdint>
#include <cstddef>
#include <initializer_list>

// Problem constants
#define WE    300
#define TEF   10
#define SLEN  24
#define HL    75      // H_LSTM
#define G4    300     // 4*HL
#define HG    77      // H_GRU
#define G3    231     // 3*HG
#define CLS   27
#define DIN   7210
#define NSTEP 4608
#define LBI   16      // LSTM segment burn-in (first emitted window gets >=28 warm steps at S=18)

typedef short    s16x8 __attribute__((ext_vector_type(8)));
typedef float    f32x4 __attribute__((ext_vector_type(4)));
typedef _Float16 f16x8 __attribute__((ext_vector_type(8)));
typedef _Float16 f16x4 __attribute__((ext_vector_type(4)));

static __device__ __forceinline__ unsigned short f2bf(float f) {
  unsigned u = __builtin_bit_cast(unsigned, f);
  unsigned r = u + 0x7fffu + ((u >> 16) & 1u);   // RNE
  return (unsigned short)(r >> 16);
}
static __device__ __forceinline__ unsigned packbf(float2 v) {
  return (unsigned)f2bf(v.x) | ((unsigned)f2bf(v.y) << 16);
}

static __device__ __forceinline__ float fast_exp2(float x) {
#if __has_builtin(__builtin_amdgcn_exp2f)
  return __builtin_amdgcn_exp2f(x);
#else
  return __exp2f(x);
#endif
}
static __device__ __forceinline__ float fast_rcp(float x) {
#if __has_builtin(__builtin_amdgcn_rcpf)
  return __builtin_amdgcn_rcpf(x);
#else
  return 1.0f / x;
#endif
}
static __device__ __forceinline__ float sigm(float x) {
  return fast_rcp(1.0f + fast_exp2(-1.4426950408889634f * x));
}
static __device__ __forceinline__ float tanh_f(float x) {
  return 2.0f * fast_rcp(1.0f + fast_exp2(-2.8853900817779268f * x)) - 1.0f;
}

// LDS-only barrier (global prefetch stays in flight)
static __device__ __forceinline__ void lds_barrier() {
  __asm__ volatile("s_waitcnt lgkmcnt(0)\n\ts_barrier" ::: "memory");
}

// ---------------------------------------------------------------------------
// Wt2 K-TILED: Wt2[kb][n][kk] = lstm_W[kb*32+kk][orig(n)], bf16, [10][320][32].
// Column permutation n = 4*e + gate (orig = gate*75+e).
// ---------------------------------------------------------------------------
__global__ __launch_bounds__(256) void k_prep_wt(const float* __restrict__ W,
                                                 unsigned short* __restrict__ Wt2) {
  int idx = blockIdx.x * 256 + threadIdx.x;
  if (idx >= 320 * 320) return;
  int n = idx / 320, k = idx - n * 320;
  float v = 0.0f;
  if (n < G4 && k < WE) {
    int e = n >> 2, g = n & 3;
    v = W[k * G4 + (g * 75 + e)];
  }
  size_t dst = ((size_t)(k >> 5) * 320 + n) * 32 + (k & 31);
  Wt2[dst] = f2bf(v);
}

// Upp[c][k] f16, [304][96]: Upp[c][k] = lstm_U[k][orig(c)], zero-padded.
__global__ __launch_bounds__(256) void k_prep_u(const float* __restrict__ U,
                                                unsigned short* __restrict__ Upp) {
  int idx = blockIdx.x * 256 + threadIdx.x;
  if (idx >= 304 * 96) return;
  int c = idx / 96, k = idx - c * 96;
  float v = 0.f;
  int e = c >> 2, g = c & 3;
  if (e < HL && k < HL) v = U[k * G4 + g * 75 + e];
  _Float16 hv = (_Float16)v;
  Upp[idx] = __builtin_bit_cast(unsigned short, hv);
}

// ---------------------------------------------------------------------------
// K1 v4 (r10): XWc(f16) = we @ lstm_W + lstm_b. Single dispatch again, with
// XCD-AWARE PAIRING: the two N-halves of an M-block previously came from
// blockIdx.y (r8: both fetch the same 128 X-rows from HBM -> FETCH 290 MB vs
// 130 analytic; r9's dispatch split removed even temporal adjacency).
// Remap: v -> g=v>>4, r=v&15, y=r>>3, mblk=g*8+(r&7). Pair members (v, v+8)
// share v%8 -> same XCD under round-robin placement AND are ~8 dispatch
// slots apart -> the 2nd A-read hits that XCD's private L2.
// Everything else identical to the r8/r9-verified kernel.
// ---------------------------------------------------------------------------
__global__ __launch_bounds__(512) void k_gemm(const float* __restrict__ X,
                                              const unsigned short* __restrict__ Wt2,
                                              const float* __restrict__ bvec,
                                              unsigned short* __restrict__ XWh,
                                              int n0, int NB) {
  __shared__ __align__(16) uint4 Ab[2][640];   // slot = rowA*5 + qtr   (20.5 KB)
  __shared__ __align__(16) uint4 Bb[2][800];   // slot = row*5 + sub    (25.6 KB)
  const int tid = threadIdx.x;
  const int wave = tid >> 6, lane = tid & 63;

  // pairing remap (fallback to plain split if NB not a multiple of 8)
  const int v = blockIdx.x;
  int mblk, ny;
  if ((NB & 7) == 0) {
    const int g = v >> 4, r = v & 15;
    ny = r >> 3;
    mblk = g * 8 + (r & 7);
  } else {
    ny = (v >= NB) ? 1 : 0;
    mblk = ny ? (v - NB) : v;
  }
  const int mlo = mblk * 128;
  const int nbase = ny * 160;
  const int mrow = lane & 15, q4 = lane >> 4;

  // A staging: thread covers row rowA (0..127), bf16-cols [kb*32+qtr*8, +8)
  const int rowA = tid >> 2, qtr = tid & 3;
  const int mg = n0 * 24 + mlo + rowA;
  const int an = mg / 24, at = mg - an * 24;
  const float2* asrc2 = (const float2*)(X + (size_t)an * DIN + at * WE);  // 8B-aligned

  // B staging: 16B chunk o of the 640-chunk slab [kb][nbase..nbase+160][32]
  const int o0 = tid, o1 = tid + 512;
  const bool h1 = (tid < 128);
  const unsigned short* bsrc = Wt2 + (size_t)nbase * 32;   // + kb*10240 per kb

  f32x4 acc[10];
#pragma unroll
  for (int j = 0; j < 10; ++j) { acc[j][0] = 0.f; acc[j][1] = 0.f; acc[j][2] = 0.f; acc[j][3] = 0.f; }

  // prologue: stage kb=0 into buf 0
  {
    float2 af2[4];
#pragma unroll
    for (int p = 0; p < 4; ++p) af2[p] = asrc2[(qtr * 8 + 2 * p) >> 1];  // cols <= 30 < 300
    uint4 r0 = *(const uint4*)(bsrc + (size_t)o0 * 8);
    uint4 r1 = h1 ? *(const uint4*)(bsrc + (size_t)o1 * 8) : uint4{0, 0, 0, 0};
    uint4 w0;
    w0.x = packbf(af2[0]); w0.y = packbf(af2[1]); w0.z = packbf(af2[2]); w0.w = packbf(af2[3]);
    Ab[0][rowA * 5 + qtr] = w0;
    Bb[0][(o0 >> 2) * 5 + (o0 & 3)] = r0;
    if (h1) Bb[0][(o1 >> 2) * 5 + (o1 & 3)] = r1;
  }
  __syncthreads();

  for (int kb = 0; kb < 10; ++kb) {
    const int par = kb & 1;
    float2 af2[4];
    uint4 r0, r1;
    if (kb < 9) {
      const int base = (kb + 1) * 32 + qtr * 8;
#pragma unroll
      for (int p = 0; p < 4; ++p) {
        int cc = base + 2 * p;
        if (cc < WE) af2[p] = asrc2[cc >> 1];
        else { af2[p].x = 0.f; af2[p].y = 0.f; }
      }
      const unsigned short* bk = bsrc + (size_t)(kb + 1) * 10240;  // 320*32
      r0 = *(const uint4*)(bk + (size_t)o0 * 8);
      if (h1) r1 = *(const uint4*)(bk + (size_t)o1 * 8);
    }
    s16x8 fa = __builtin_bit_cast(s16x8, Ab[par][(wave * 16 + mrow) * 5 + q4]);
#pragma unroll
    for (int ni = 0; ni < 10; ++ni) {
      s16x8 fb = __builtin_bit_cast(s16x8, Bb[par][(ni * 16 + mrow) * 5 + q4]);
      acc[ni] = __builtin_amdgcn_mfma_f32_16x16x32_bf16(fa, fb, acc[ni], 0, 0, 0);
    }
    if (kb < 9) {
      uint4 w0;
      w0.x = packbf(af2[0]); w0.y = packbf(af2[1]); w0.z = packbf(af2[2]); w0.w = packbf(af2[3]);
      Ab[par ^ 1][rowA * 5 + qtr] = w0;
      Bb[par ^ 1][(o0 >> 2) * 5 + (o0 & 3)] = r0;
      if (h1) Bb[par ^ 1][(o1 >> 2) * 5 + (o1 & 3)] = r1;
    }
    __syncthreads();
  }

  // epilogue: C layout col=lane&15, row=(lane>>4)*4+reg; bias via orig(col); f16 store
#pragma unroll
  for (int ni = 0; ni < 10; ++ni) {
    int col = nbase + ni * 16 + mrow;
    if (col < G4) {
      int orig = (col & 3) * 75 + (col >> 2);
      float bv = bvec[orig];
#pragma unroll
      for (int reg = 0; reg < 4; ++reg) {
        int m = mlo + wave * 16 + q4 * 4 + reg;
        _Float16 hv = (_Float16)(acc[ni][reg] + bv);
        XWh[(size_t)m * G4 + col] = __builtin_bit_cast(unsigned short, hv);
      }
    }
  }
}

// ---------------------------------------------------------------------------
// K2: t-split MFMA batched-chain LSTM (r9-verified; t-split kept — null
// perf delta but halves LDS and VGPR state). 2 blocks per segment (t 0-11 /
// 12-23), grid 2*nseg, 2 blocks/CU. Z = U_perm(304x96 f16, regs) @ H(16x96
// f16, LDS dbuf) via mfma_f32_16x16x32_f16; activation lane-local via
// gate-interleaved columns. NULL t-split result (r9) => k_lstm is per-CU
// throughput-bound; further split won't pay.
// ---------------------------------------------------------------------------
#define NTMAX 3

#define LSTM_STEP2(MM, BUF, XC)                                                        \
  {                                                                                    \
    const int mm = (MM);                                                               \
    f16x8 hf[3];                                                                       \
    _Pragma("unroll")                                                                  \
    for (int kg = 0; kg < 3; ++kg)                                                     \
      hf[kg] = *(const f16x8*)&Hl[BUF][lm][kg * 32 + lk * 8];                          \
    f32x4 ac[NTMAX];                                                                   \
    _Pragma("unroll")                                                                  \
    for (int i = 0; i < NTMAX; ++i) if (i < NT) {                                      \
      f32x4 a = {0.f, 0.f, 0.f, 0.f};                                                  \
      a = __builtin_amdgcn_mfma_f32_16x16x32_f16(u[i][0], hf[0], a, 0, 0, 0);          \
      a = __builtin_amdgcn_mfma_f32_16x16x32_f16(u[i][1], hf[1], a, 0, 0, 0);          \
      a = __builtin_amdgcn_mfma_f32_16x16x32_f16(u[i][2], hf[2], a, 0, 0, 0);          \
      ac[i] = a;                                                                       \
    }                                                                                  \
    const int ng = gbase + mm;                                                         \
    const int bi = ng / 18;                                                            \
    const int rr = ng - bi * 18;                                                       \
    const bool win = (rr >= 12);                                                       \
    float aw = 0.f;                                                                    \
    if (win)                                                                           \
      aw = (rr == 12) ? aA[0] : (rr == 13) ? aA[1] : (rr == 14) ? aA[2]                \
         : (rr == 15) ? aA[3] : (rr == 16) ? aA[4] : aA[5];                            \
    const bool fl = (rr == 17) && (ng >= out_lo);                                      \
    const bool ldok = (mm + 2 < count);                                                \
    _Pragma("unroll")                                                                  \
    for (int i = 0; i < NTMAX; ++i) if (i < NT) {                                      \
      const int e = (w + 8 * i) * 4 + lk;                                              \
      const bool val = (lm < 12) && (e < HL);                                          \
      f32x4 z4 = ac[i] + __builtin_convertvector(XC[i], f32x4);                        \
      if (ldok && val)                                                                 \
        XC[i] = __builtin_bit_cast(f16x4,                                              \
          *(const uint2*)(Xh + ((size_t)(start + mm + 2) * 24 + tg) * G4 + 4 * e));    \
      float si = sigm(z4[0]);                                                          \
      float sf = sigm(z4[1]);                                                          \
      float tgv = tanh_f(z4[2]);                                                       \
      float so = sigm(z4[3]);                                                          \
      float c = fmaf(sf, cst[i], si * tgv);                                            \
      cst[i] = c;                                                                      \
      float h = so * tanh_f(c);                                                        \
      hlv[i] = h;                                                                      \
      if (val) {                                                                       \
        _Float16 hh = (_Float16)h;                                                     \
        Hl[(BUF) ^ 1][lm][e] = __builtin_bit_cast(unsigned short, hh);                 \
      }                                                                                \
      if (win) {                                                                       \
        accA[i] = fmaf(aw, h, accA[i]);                                                \
        if (fl) {                                                                      \
          if (val) P[((size_t)((tg << 8) + bi)) * 76 + e] = accA[i];                   \
          accA[i] = 0.f;                                                               \
        }                                                                              \
      }                                                                                \
    }                                                                                  \
    lds_barrier();                                                                     \
  }

__global__ __launch_bounds__(512) void k_lstm(const unsigned short* __restrict__ Xh,
                                              const unsigned short* __restrict__ Upp,
                                              const float* __restrict__ Atw,
                                              float* __restrict__ P,
                                              float* __restrict__ Sbuf,
                                              int n0, int S, int nseg,
                                              int first, int parity) {
  __shared__ __align__(16) unsigned short Hl[2][16][104];  // 6.7 KB, dbuf
  const int tid = threadIdx.x;
  const int w = tid >> 6, l = tid & 63;
  const int lm = l & 15;          // local t (chain) / B fragment col
  const int lk = l >> 4;          // 0..3: e_local; k-subgroup
  const int seg = blockIdx.x >> 1;
  const int t0 = (blockIdx.x & 1) * 12;
  const int tg = t0 + lm;         // global chain id (valid when lm < 12)
  const int NT = (w < 3) ? 3 : 2; // M-tiles {w, w+8, w+16(w<3)} cover 0..18

  const int start = seg * S - (seg ? LBI : 0);
  const int count = S + (seg ? LBI : 0);
  const int gbase = n0 + start;
  const int out_lo = n0 + seg * S;

  f16x8 u[NTMAX][3];
#pragma unroll
  for (int i = 0; i < NTMAX; ++i) if (i < NT) {
    const int col = (w + 8 * i) * 16 + lm;   // <= 303
#pragma unroll
    for (int kg = 0; kg < 3; ++kg)
      u[i][kg] = __builtin_bit_cast(f16x8, *(const uint4*)(Upp + (size_t)col * 96 + kg * 32 + lk * 8));
  }

  float aA[6];
#pragma unroll
  for (int k = 0; k < 6; ++k) aA[k] = Atw[k];

  {
    unsigned* hz = (unsigned*)&Hl[0][0][0];
    for (int i = tid; i < 2 * 16 * 104 / 2; i += 512) hz[i] = 0;
  }

  float cst[NTMAX], hlv[NTMAX], accA[NTMAX];
#pragma unroll
  for (int i = 0; i < NTMAX; ++i) { cst[i] = 0.f; hlv[i] = 0.f; accA[i] = 0.f; }

  __syncthreads();  // Hl zero visible

  if (seg == 0 && !first) {
#pragma unroll
    for (int i = 0; i < NTMAX; ++i) if (i < NT) {
      const int e = (w + 8 * i) * 4 + lk;
      if (lm < 12 && e < HL) {
        const float* Sp = Sbuf + (size_t)(parity * 24 + tg) * 160;
        cst[i] = Sp[e];
        float hv = Sp[80 + e];
        hlv[i] = hv;
        _Float16 hh = (_Float16)hv;
        Hl[0][lm][e] = __builtin_bit_cast(unsigned short, hh);
      }
    }
  }

  f16x4 XA[NTMAX], XB[NTMAX];
#pragma unroll
  for (int i = 0; i < NTMAX; ++i) {
    XA[i] = __builtin_bit_cast(f16x4, uint2{0, 0});
    XB[i] = __builtin_bit_cast(f16x4, uint2{0, 0});
  }
#pragma unroll
  for (int i = 0; i < NTMAX; ++i) if (i < NT) {
    const int e = (w + 8 * i) * 4 + lk;
    if (lm < 12 && e < HL) {
      XA[i] = __builtin_bit_cast(f16x4, *(const uint2*)(Xh + ((size_t)(start + 0) * 24 + tg) * G4 + 4 * e));
      XB[i] = __builtin_bit_cast(f16x4, *(const uint2*)(Xh + ((size_t)(start + 1) * 24 + tg) * G4 + 4 * e));
    }
  }
  __syncthreads();  // initial h visible

  for (int m = 0; m < count; m += 2) {
    LSTM_STEP2(m,     0, XA)
    LSTM_STEP2(m + 1, 1, XB)
  }

  if (seg == nseg - 1) {
#pragma unroll
    for (int i = 0; i < NTMAX; ++i) if (i < NT) {
      const int e = (w + 8 * i) * 4 + lk;
      if (lm < 12 && e < HL) {
        float* Sp = Sbuf + (size_t)((parity ^ 1) * 24 + tg) * 160;
        Sp[e] = cst[i];
        Sp[80 + e] = hlv[i];
      }
    }
  }
}

// ---------------------------------------------------------------------------
// K3: hA -> ctx (ut==2) -> xg = ctx@gru_W + gru_b[0]. grid 256, 320 thr.
// ---------------------------------------------------------------------------
__global__ __launch_bounds__(320) void k_ctx(const float* __restrict__ P,
                                             const float* __restrict__ Wtw,
                                             const float* __restrict__ btw,
                                             const float* __restrict__ Atw,
                                             const float* __restrict__ Btw,
                                             const float* __restrict__ X,
                                             const float* __restrict__ Wg,
                                             const float* __restrict__ bg,
                                             float* __restrict__ xg) {
  __shared__ float hA[76];
  __shared__ float ctx[312];
  const int b = blockIdx.x, j = threadIdx.x;
  if (j < HL) {
    float s = 0.f;
    for (int t = 0; t < SLEN; ++t) s += P[((t << 8) + b) * 76 + j];
    hA[j] = s * (1.0f / 24.0f);
  }
  __syncthreads();
  if (j < G4) {
    float SA = Atw[0] + Atw[1] + Atw[2] + Atw[3] + Atw[4] + Atw[5];
    float s = SA * btw[j];
    for (int k = 0; k < HL; ++k) s = fmaf(hA[k], Wtw[k * G4 + j], s);
    ctx[j] = s * (1000.0f / 1001.0f) + Btw[0];
  } else if (j < 310) {
    int f = j - G4;
    float s = 0.f;
#pragma unroll
    for (int nt = 0; nt < 6; ++nt)
      s = fmaf(Atw[nt], X[(size_t)((b * 3 + 2) * 6 + nt) * DIN + 7200 + f], s);
    ctx[j] = s * (1.0f / 1001.0f) + Btw[0];
  }
  __syncthreads();
  if (j < G3) {
    float s = bg[j];
    for (int f = 0; f < 310; ++f) s = fmaf(ctx[f], Wg[f * G3 + j], s);
    xg[b * 240 + j] = s;
  }
}

// ---------------------------------------------------------------------------
// K5: segmented GRU (chain ut==2). grid 16 blocks x 256 thr.
// ---------------------------------------------------------------------------
#define GRU_STEP(B, PF)                                                                \
  {                                                                                    \
    if (q < G3) {                                                                      \
      const float4* h4 = (const float4*)gh;                                            \
      float a0 = b1, a1 = 0.f, a2 = 0.f, a3 = 0.f;                                     \
      _Pragma("unroll")                                                                \
      for (int p = 0; p < 20; ++p) {                                                   \
        float4 hv = h4[p];                                                             \
        a0 = fmaf(ug[4 * p + 0], hv.x, a0);                                            \
        a1 = fmaf(ug[4 * p + 1], hv.y, a1);                                            \
        a2 = fmaf(ug[4 * p + 2], hv.z, a2);                                            \
        a3 = fmaf(ug[4 * p + 3], hv.w, a3);                                            \
      }                                                                                \
      float rs = (a0 + a1) + (a2 + a3);                                                \
      float pnew = ((B) + 2 < 256) ? xg[((B) + 2) * 240 + q] : 0.f;                    \
      if (q < HG) {                                                                    \
        zreg = sigm((PF) + rs);                                                        \
      } else if (q < 154) {                                                            \
        rbuf[q - 77] = sigm((PF) + rs);                                                \
      } else {                                                                         \
        xkeep = (PF);                                                                  \
        rkeep = rs;                                                                    \
      }                                                                                \
      (PF) = pnew;                                                                     \
    }                                                                                  \
    lds_barrier();                                                                     \
    if (q >= 154 && q < G3) hhb[q - 154] = tanh_f(xkeep + rbuf[q - 154] * rkeep);      \
    lds_barrier();                                                                     \
    if (q < HG) {                                                                      \
      float hh = hhb[q];                                                               \
      hq = zreg * hq + (1.0f - zreg) * hh;                                             \
      gh[q] = hq;                                                                      \
      if ((B) >= out_lo) Hg[(B) * 80 + q] = hq;                                        \
    }                                                                                  \
    lds_barrier();                                                                     \
  }

__global__ __launch_bounds__(256) void k_gru(const float* __restrict__ Ug,
                                             const float* __restrict__ bg,
                                             const float* __restrict__ xg,
                                             float* __restrict__ Hg) {
  __shared__ __align__(16) float gh[80];
  __shared__ float rbuf[77];
  __shared__ float hhb[77];
  const int q = threadIdx.x;
  const int b0 = blockIdx.x;
  const int out_lo = b0 * 16;
  const int start = b0 ? (out_lo - 16) : 0;
  const int end = out_lo + 16;
  float ug[80];
  float b1 = 0.f;
  if (q < G3) {
    b1 = bg[G3 + q];
#pragma unroll
    for (int k = 0; k < 80; ++k) ug[k] = (k < HG) ? Ug[k * G3 + q] : 0.f;
  }
  if (q < 80) gh[q] = 0.f;
  float hq = 0.f, zreg = 0.f, xkeep = 0.f, rkeep = 0.f;
  float pf0 = (q < G3) ? xg[start * 240 + q] : 0.f;
  float pf1 = (q < G3) ? xg[(start + 1) * 240 + q] : 0.f;
  __syncthreads();
  for (int b = start; b < end; b += 2) {
    GRU_STEP(b, pf0)
    GRU_STEP(b + 1, pf1)
  }
}

// ---------------------------------------------------------------------------
__global__ __launch_bounds__(64) void k_out(const float* __restrict__ Hg,
                                            const float* __restrict__ Wl,
                                            const float* __restrict__ bl,
                                            float* __restrict__ out) {
  __shared__ float lb[CLS];
  __shared__ float eb[CLS];
  const int b = blockIdx.x, j = threadIdx.x;
  float lg = 0.f;
  if (j < CLS) {
    lg = bl[j];
    for (int k = 0; k < HG; ++k) lg = fmaf(Hg[b * 80 + k], Wl[k * CLS + j], lg);
    lb[j] = lg;
  }
  __syncthreads();
  float ex = 0.f;
  if (j < CLS) {
    float m = lb[0];
    for (int i = 1; i < CLS; ++i) m = fmaxf(m, lb[i]);
    ex = fast_exp2((lg - m) * 1.4426950408889634f);
    eb[j] = ex;
  }
  __syncthreads();
  if (j < CLS) {
    float s = 0.f;
    for (int i = 0; i < CLS; ++i) s += eb[i];
    out[b * CLS + j] = ex / s;
  }
}

// ---------------------------------------------------------------------------
extern "C" void kernel_launch(void* const* d_in, const int* in_sizes, int n_in,
                              void* d_out, int out_size, void* d_ws, size_t ws_size,
                              hipStream_t stream) {
  const float* X    = (const float*)d_in[0];
  const float* lW   = (const float*)d_in[1];
  const float* lU   = (const float*)d_in[2];
  const float* lb   = (const float*)d_in[3];
  const float* twW  = (const float*)d_in[4];
  const float* twb  = (const float*)d_in[5];
  const float* Atw  = (const float*)d_in[6];
  const float* Btw  = (const float*)d_in[7];
  const float* gW   = (const float*)d_in[8];
  const float* gU   = (const float*)d_in[9];
  const float* gb   = (const float*)d_in[10];
  const float* linW = (const float*)d_in[11];
  const float* linb = (const float*)d_in[12];
  float* out = (float*)d_out;

  char* ws = (char*)d_ws;
  unsigned short* Wt = (unsigned short*)(ws + 0);        // 204800 (k-tiled [10][320][32])
  unsigned short* Up = (unsigned short*)(ws + 204800);   // 58368 (304x96 f16)
  float* P   = (float*)(ws + 263168);                    // 1867776
  float* Sb  = (float*)(ws + 2130944);                   // 30720
  float* xg  = (float*)(ws + 2161664);                   // 245760
  float* Hg  = (float*)(ws + 2407424);                   // 81920
  unsigned short* XWc = (unsigned short*)(ws + 2489344); // NC*24*300*2 (full: 66.4 MB, f16)

  const size_t fixed = 2489344;
  int NC = 144;
  for (int k : {32, 16, 8, 4, 2, 1}) {
    size_t need = fixed + (size_t)144 * k * 14400;
    if (need <= ws_size) { NC = 144 * k; break; }
  }
  const int chunks = NSTEP / NC;
  // S=18: one 18-window per segment; nseg = NC/18 <= 256; k_lstm grid is
  // 2*nseg (t-split) -> 512 blocks = 2/CU.
  int S = NC, nseg = 1;
  for (int s : {18, 24, 48, 96, 192, 288, 576}) {
    if (NC % s == 0 && NC / s <= 256) { S = s; nseg = NC / s; break; }
  }

  k_prep_wt<<<dim3(400), dim3(256), 0, stream>>>(lW, Wt);
  k_prep_u<<<dim3(114), dim3(256), 0, stream>>>(lU, Up);
  for (int ci = 0; ci < chunks; ++ci) {
    const int n0 = ci * NC;
    const int NB = NC * 24 / 128;
    k_gemm<<<dim3(NB * 2), dim3(512), 0, stream>>>(X, Wt, lb, XWc, n0, NB);
    k_lstm<<<dim3(nseg * 2), dim3(512), 0, stream>>>(XWc, Up, Atw, P, Sb,
                                                     n0, S, nseg,
                                                     ci == 0 ? 1 : 0, ci & 1);
  }
  k_ctx<<<dim3(256), dim3(320), 0, stream>>>(P, twW, twb, Atw, Btw, X, gW, gb, xg);
  k_gru<<<dim3(16), dim3(256), 0, stream>>>(gU, gb, xg, Hg);
  k_out<<<dim3(256), dim3(64), 0, stream>>>(Hg, linW, linb, out);
}